// Round 2
// baseline (16490.129 us; speedup 1.0000x reference)
//
#include <hip/hip_runtime.h>
#include <cstdint>
#include <cstddef>

// ---------------------------------------------------------------------------
// ConditionedPNA on MI355X. Batch-sequential, exact stable-top-k via radix
// select + deterministic rank scan, CSR-based PNA aggregation (no float
// atomics), readlane-broadcast register GEMMs for PNA/score MLPs.
// Workspace requirement: ~73.4 MB (assumed available in d_ws).
// NOTE: all atomics use pointer-arithmetic form (arr + i) -- the source
// pipeline HTML-decodes "&"+identifier sequences (e.g. "&deg...").
// ---------------------------------------------------------------------------

#define NN   50000
#define NEG  1600000
#define NDIM 64
#define NR2  1000
#define NTC  32
#define NMI  10000
#define KSEL 5000u
#define ESEL 160000u
#define KEY_NEG_INF 0x007FFFFFu

#define RL(x,k) __int_as_float(__builtin_amdgcn_readlane(__float_as_int(x),(k)))

__device__ inline unsigned fkey(float f){
  unsigned u = __float_as_uint(f);
  if ((u << 1) == 0u) u = 0u;                    // canonicalize -0 -> +0
  return (u & 0x80000000u) ? ~u : (u | 0x80000000u);
}

__device__ inline float waveSumF(float v){
  #pragma unroll
  for (int d = 1; d < 64; d <<= 1) v += __shfl_xor(v, d);
  return v;
}

// ------------------------------- setup kernels ------------------------------

__global__ void k_lastm(const int* __restrict__ all_index, int* __restrict__ lastm){
  int i = blockIdx.x * 256 + threadIdx.x;
  if (i < NMI) atomicMax(lastm + all_index[i], i);
}

__global__ void k_degfull(const int* __restrict__ esrc, unsigned* __restrict__ dcnt){
  int i = blockIdx.x * 256 + threadIdx.x;
  if (i < NEG) atomicAdd(dcnt + esrc[i], 1u);
}

__global__ void k_dsum(const unsigned* __restrict__ dcnt, float* __restrict__ stF){
  int i = blockIdx.x * 256 + threadIdx.x;
  float v = (i < NN) ? logf((float)dcnt[i] + 1.f) : 0.f;
  v = waveSumF(v);
  if ((threadIdx.x & 63) == 0) atomicAdd(stF + 4, v);
}

__global__ void k_finalize(float* __restrict__ stF, const float* __restrict__ b1,
                           const float* __restrict__ w2, const float* __restrict__ b2){
  stF[5] = stF[4] / (float)NN;                  // dmean
  float s = 0.f;
  for (int m = 0; m < 128; m++) s += fmaxf(b1[m], 0.f) * w2[m];
  stF[6] = s + b2[0];                           // base score for zero hidden
}

// ----------------------------- per-batch init -------------------------------

__global__ void k_relb(const int* __restrict__ r_index, const float* __restrict__ hs,
                       const float* __restrict__ rel_table, const float* __restrict__ lw,
                       const float* __restrict__ lb, const float* __restrict__ w1,
                       const float* __restrict__ b1, const float* __restrict__ w2,
                       const float* __restrict__ b2, float* __restrict__ relb,
                       float* __restrict__ stF, int b){
  int j = threadIdx.x;                          // 64 threads, 1 wave
  int r = r_index[b];
  float acc = lb[j];
  for (int k = 0; k < 64; k++) acc = fmaf(rel_table[(size_t)r*64 + k], lw[(64 + k)*64 + j], acc);
  relb[j] = acc;
  // score of head embedding
  float heur = acc;
  for (int k = 0; k < 64; k++) heur = fmaf(hs[b*64 + k], lw[k*64 + j], heur);
  float x = hs[b*64 + j] * heur;
  float o = 0.f;
  for (int half = 0; half < 2; half++){
    float a = b1[half*64 + j];
    for (int k = 0; k < 64; k++) a = fmaf(__shfl(x, k), w1[k*128 + half*64 + j], a);
    o = fmaf(fmaxf(a, 0.f), w2[half*64 + j], o);
  }
  o = waveSumF(o);
  if (j == 0) stF[7] = o + b2[0];
}

__global__ void k_inithidden(const int* __restrict__ lastm, const float* __restrict__ ste,
                             const float* __restrict__ hs, const int* __restrict__ h_index,
                             int b, float* __restrict__ hidden){
  int idx = blockIdx.x * 256 + threadIdx.x;     // grid covers NN*64 exactly
  int n = idx >> 6, j = idx & 63;
  int h = h_index[b];
  float v = 0.f;
  int lm = lastm[n];
  if (lm >= 0) v = ste[(size_t)lm*64 + j];
  if (n == h)  v = hs[b*64 + j];
  hidden[idx] = v;
}

__global__ void k_initscore(const int* __restrict__ h_index, int b,
                            const float* __restrict__ stF, float* __restrict__ score){
  int i = blockIdx.x * 256 + threadIdx.x;
  if (i < NN) score[i] = (i == h_index[b]) ? stF[7] : stF[6];
}

// ------------------------------ top-k machinery -----------------------------

__global__ void k_nkey(const float* __restrict__ score, unsigned* __restrict__ nkey,
                       unsigned* __restrict__ st){
  int i = blockIdx.x * 256 + threadIdx.x;
  if (i < NN) nkey[i] = fkey(score[i]);
  if (i == 0){ st[0] = 0u; st[1] = KSEL; }
}

__global__ void k_ekey(const int* __restrict__ esrc, const int* __restrict__ edst,
                       const unsigned* __restrict__ nsel, const float* __restrict__ score,
                       unsigned* __restrict__ ekey, unsigned* __restrict__ st){
  int i = blockIdx.x * 256 + threadIdx.x;
  if (i < NEG) ekey[i] = nsel[esrc[i]] ? fkey(score[edst[i]]) : KEY_NEG_INF;
  if (i == 0){ st[0] = 0u; st[1] = ESEL; st[2] = 0u; }
}

// wave-aggregated 16-bit-digit histogram (handles massive key ties cheaply)
__global__ void k_hist16(const unsigned* __restrict__ keys, int n, int pass,
                         const unsigned* __restrict__ st, unsigned* __restrict__ hist){
  int i = blockIdx.x * 256 + threadIdx.x;
  unsigned bin = 0xFFFFFFFFu;
  if (i < n){
    unsigned k = keys[i];
    if (pass == 1) bin = k >> 16;
    else { if ((k >> 16) == (st[0] >> 16)) bin = k & 0xFFFFu; }
  }
  bool active = (bin != 0xFFFFFFFFu);
  int lane = threadIdx.x & 63;
  while (__any((int)active)){
    unsigned long long mask = __ballot((int)active);
    int leader = __ffsll((unsigned long long)mask) - 1;
    unsigned lbin = (unsigned)__shfl((int)bin, leader);
    bool same = active && (bin == lbin);
    unsigned long long smask = __ballot((int)same);
    if (lane == leader) atomicAdd(hist + lbin, (unsigned)__popcll(smask));
    if (same) active = false;
  }
}

// single block: find digit containing the R-th largest; update prefix/R; zero hist
__global__ __launch_bounds__(1024) void k_pick16(int pass, unsigned* __restrict__ st,
                                                 unsigned* __restrict__ hist){
  __shared__ unsigned csum[1024];
  __shared__ unsigned sc[1024];
  int t = threadIdx.x;
  unsigned R = st[1];
  unsigned s = 0;
  for (int b = 0; b < 64; b++) s += hist[t*64 + b];
  csum[t] = s; sc[t] = s; __syncthreads();
  for (int d = 1; d < 1024; d <<= 1){
    unsigned v = (t >= d) ? sc[t - d] : 0u;
    __syncthreads();
    sc[t] += v;
    __syncthreads();
  }
  unsigned total = sc[1023];
  unsigned above = total - sc[t];               // keys in higher chunks
  unsigned cs = csum[t];
  if (above < R && above + cs >= R){
    unsigned cum = above;
    for (int b = 63; b >= 0; b--){
      unsigned c = hist[t*64 + b];
      if (cum + c >= R){
        unsigned bstar = (unsigned)(t*64 + b);
        if (pass == 1) st[0] = bstar << 16; else st[0] = st[0] | bstar;
        st[1] = R - cum;
        break;
      }
      cum += c;
    }
  }
  for (int b = 0; b < 64; b++) hist[t*64 + b] = 0u;   // leave hist zeroed
}

__global__ __launch_bounds__(1024) void k_countEq(const unsigned* __restrict__ keys, int n,
                                                  const unsigned* __restrict__ st,
                                                  unsigned* __restrict__ blockcnt){
  int i = blockIdx.x * 1024 + threadIdx.x;
  unsigned v = st[0];
  bool eq = (i < n) && (keys[i] == v);
  unsigned long long bal = __ballot((int)eq);
  __shared__ unsigned wsh[16];
  int wid = threadIdx.x >> 6, lane = threadIdx.x & 63;
  if (lane == 0) wsh[wid] = (unsigned)__popcll(bal);
  __syncthreads();
  if (threadIdx.x == 0){
    unsigned tot = 0;
    for (int w = 0; w < 16; w++) tot += wsh[w];
    blockcnt[blockIdx.x] = tot;
  }
}

__global__ __launch_bounds__(1024) void k_scanBlocks(unsigned* __restrict__ blockcnt, int nb){
  __shared__ unsigned sc[2048];
  int t = threadIdx.x;
  unsigned a  = (t < nb) ? blockcnt[t] : 0u;
  unsigned b2 = (1024 + t < nb) ? blockcnt[1024 + t] : 0u;
  sc[t] = a; sc[1024 + t] = b2; __syncthreads();
  for (int d = 1; d < 2048; d <<= 1){
    unsigned v1 = (t >= d) ? sc[t - d] : 0u;
    unsigned v2 = (1024 + t >= d) ? sc[1024 + t - d] : 0u;
    __syncthreads();
    sc[t] += v1; sc[1024 + t] += v2;
    __syncthreads();
  }
  if (t < nb) blockcnt[t] = sc[t] - a;              // exclusive
  if (1024 + t < nb) blockcnt[1024 + t] = sc[1024 + t] - b2;
}

__global__ __launch_bounds__(1024) void k_selNodes(const unsigned* __restrict__ keys, int n,
                                                   const unsigned* __restrict__ st,
                                                   const unsigned* __restrict__ blockcnt,
                                                   unsigned* __restrict__ nsel){
  int i = blockIdx.x * 1024 + threadIdx.x;
  unsigned v = st[0], R = st[1];
  unsigned k = (i < n) ? keys[i] : 0u;
  bool eq = (i < n) && (k == v);
  unsigned long long bal = __ballot((int)eq);
  __shared__ unsigned wsh[16];
  int wid = threadIdx.x >> 6, lane = threadIdx.x & 63;
  if (lane == 0) wsh[wid] = (unsigned)__popcll(bal);
  __syncthreads();
  unsigned woff = 0;
  for (int w = 0; w < wid; w++) woff += wsh[w];
  unsigned lpre = (unsigned)__popcll(bal & ((1ull << lane) - 1ull));
  unsigned rank = blockcnt[blockIdx.x] + woff + lpre;
  if (i < n) nsel[i] = (k > v || (eq && rank < R)) ? 1u : 0u;
}

// select + compact valid edges; also zero DCNT for this layer
__global__ __launch_bounds__(1024) void k_selEdgesCompact(const unsigned* __restrict__ keys, int n,
                                                          unsigned* __restrict__ st,
                                                          const unsigned* __restrict__ blockcnt,
                                                          unsigned* __restrict__ elist,
                                                          unsigned* __restrict__ dcnt){
  int i = blockIdx.x * 1024 + threadIdx.x;
  if (i < NN) dcnt[i] = 0u;
  unsigned v = st[0], R = st[1];
  unsigned k = (i < n) ? keys[i] : 0u;
  bool eq = (i < n) && (k == v);
  unsigned long long bal = __ballot((int)eq);
  __shared__ unsigned wsh[16];
  int wid = threadIdx.x >> 6, lane = threadIdx.x & 63;
  if (lane == 0) wsh[wid] = (unsigned)__popcll(bal);
  __syncthreads();
  unsigned woff = 0;
  for (int w = 0; w < wid; w++) woff += wsh[w];
  unsigned lpre = (unsigned)__popcll(bal & ((1ull << lane) - 1ull));
  unsigned rank = blockcnt[blockIdx.x] + woff + lpre;
  bool sel = (i < n) && (k > v || (eq && rank < R));
  bool take = sel && (k > KEY_NEG_INF);             // finite escore only
  unsigned long long m2 = __ballot((int)take);
  unsigned cnt = (unsigned)__popcll(m2);
  unsigned base = 0;
  if (lane == 0) base = atomicAdd(st + 2, cnt);
  base = (unsigned)__shfl((int)base, 0);
  if (take) elist[base + (unsigned)__popcll(m2 & ((1ull << lane) - 1ull))] = (unsigned)i;
}

// ------------------------------- CSR build ----------------------------------

__global__ void k_degcnt(const unsigned* __restrict__ elist, const int* __restrict__ edst,
                         const unsigned* __restrict__ st, unsigned* __restrict__ dcnt){
  unsigned i = blockIdx.x * 256 + threadIdx.x;
  if (i < st[2]) atomicAdd(dcnt + edst[elist[i]], 1u);
}

__global__ __launch_bounds__(1024) void k_blocksumsInt(const unsigned* __restrict__ dcnt,
                                                       unsigned* __restrict__ blockcnt){
  int i = blockIdx.x * 1024 + threadIdx.x;
  unsigned v = (i < NN) ? dcnt[i] : 0u;
  #pragma unroll
  for (int d = 1; d < 64; d <<= 1) v += (unsigned)__shfl_xor((int)v, d);
  __shared__ unsigned wsh[16];
  int wid = threadIdx.x >> 6, lane = threadIdx.x & 63;
  if (lane == 0) wsh[wid] = v;
  __syncthreads();
  if (threadIdx.x == 0){
    unsigned tot = 0;
    for (int w = 0; w < 16; w++) tot += wsh[w];
    blockcnt[blockIdx.x] = tot;
  }
}

__global__ __launch_bounds__(1024) void k_rowstart(const unsigned* __restrict__ dcnt,
                                                   const unsigned* __restrict__ blockcnt,
                                                   unsigned* __restrict__ rowstart,
                                                   unsigned* __restrict__ curs){
  int i = blockIdx.x * 1024 + threadIdx.x;
  int wid = threadIdx.x >> 6, lane = threadIdx.x & 63;
  unsigned d = (i < NN) ? dcnt[i] : 0u;
  unsigned v = d;
  #pragma unroll
  for (int dl = 1; dl < 64; dl <<= 1){
    unsigned t2 = (unsigned)__shfl_up((int)v, dl);
    if (lane >= dl) v += t2;
  }
  __shared__ unsigned wsh[16];
  if (lane == 63) wsh[wid] = v;
  __syncthreads();
  unsigned woff = 0;
  for (int w = 0; w < wid; w++) woff += wsh[w];
  unsigned excl = blockcnt[blockIdx.x] + woff + (v - d);
  if (i < NN){ rowstart[i] = excl; curs[i] = excl; }
}

__global__ void k_scatter(const unsigned* __restrict__ elist, const int* __restrict__ edst,
                          const unsigned* __restrict__ st, unsigned* __restrict__ curs,
                          unsigned* __restrict__ csr){
  unsigned i = blockIdx.x * 256 + threadIdx.x;
  if (i < st[2]){
    unsigned e = elist[i];
    unsigned pos = atomicAdd(curs + edst[e], 1u);
    csr[pos] = e;
  }
}

// --------------------------- aggregation / PNA ------------------------------

__global__ void k_aggcsr(const int* __restrict__ esrc, const int* __restrict__ etype,
                         const unsigned* __restrict__ csr, const unsigned* __restrict__ rowstart,
                         const unsigned* __restrict__ dcnt, const float* __restrict__ score,
                         const float* __restrict__ hidden, const float* __restrict__ relw_l,
                         float* __restrict__ sm, float* __restrict__ sq,
                         float* __restrict__ mx, float* __restrict__ mn){
  int w = (blockIdx.x * 256 + threadIdx.x) >> 6;
  int lane = threadIdx.x & 63;
  if (w >= NN) return;
  unsigned cnt = dcnt[w];
  if (cnt == 0u) return;
  unsigned rs = rowstart[w];
  float sm_ = 0.f, sq_ = 0.f;
  float mx_ = -__builtin_huge_valf(), mn_ = __builtin_huge_valf();
  for (unsigned ii = 0; ii < cnt; ii++){
    int e = (int)csr[rs + ii];
    int s = esrc[e], t = etype[e];
    float g = 1.f / (1.f + expf(-score[s]));
    float m = g * hidden[(size_t)s*64 + lane] * relw_l[(size_t)t*64 + lane];
    sm_ += m; sq_ = fmaf(m, m, sq_);
    mx_ = fmaxf(mx_, m); mn_ = fminf(mn_, m);
  }
  size_t off = (size_t)w*64 + lane;
  sm[off] = sm_; sq[off] = sq_; mx[off] = mx_; mn[off] = mn_;
}

__global__ __launch_bounds__(256) void k_pna(const float* __restrict__ pw, const float* __restrict__ pb,
                                             const float* __restrict__ sm, const float* __restrict__ sq,
                                             const float* __restrict__ mx, const float* __restrict__ mn,
                                             const unsigned* __restrict__ dcnt, const float* __restrict__ stF,
                                             float* __restrict__ hidden){
  int wid = threadIdx.x >> 6, lane = threadIdx.x & 63;
  int nodeBase = (blockIdx.x*4 + wid) * 64;
  if (nodeBase >= NN) return;
  float dmean = stF[5];
  float bias = pb[lane];
  for (int g0 = 0; g0 < 64; g0 += 16){
    float degv[16];
    bool anyHas = false;
    #pragma unroll
    for (int n = 0; n < 16; n++){
      int node = nodeBase + g0 + n;
      unsigned d = (node < NN) ? dcnt[node] : 0u;
      degv[n] = (float)d;
      anyHas |= (d > 0u);
    }
    if (!anyHas) continue;
    float acc[16];
    #pragma unroll
    for (int n = 0; n < 16; n++) acc[n] = bias;
    for (int c = 0; c < 12; c++){
      int a = c / 3, s = c - a*3;
      float wreg[64];
      #pragma unroll
      for (int k = 0; k < 64; k++) wreg[k] = pw[(size_t)(c*64 + k)*64 + lane];
      float fv[16];
      #pragma unroll
      for (int n = 0; n < 16; n++){
        float v = 0.f;
        if (degv[n] > 0.f){
          int node = nodeBase + g0 + n;
          size_t off = (size_t)node*64 + lane;
          float degc = fmaxf(degv[n], 1.f);
          float logd = logf(degv[n] + 1.f);
          float scaler = (s == 0) ? 1.f : ((s == 1) ? (logd / dmean) : (dmean / fmaxf(logd, 1e-6f)));
          if (a == 0)      v = sm[off] / degc;
          else if (a == 1) v = mx[off];
          else if (a == 2) v = mn[off];
          else { float me = sm[off] / degc; float qv = sq[off] / degc;
                 v = sqrtf(fmaxf(qv - me*me, 0.f) + 1e-6f); }
          v *= scaler;
        }
        fv[n] = v;
      }
      #pragma unroll
      for (int k = 0; k < 64; k++){
        float w = wreg[k];
        #pragma unroll
        for (int n = 0; n < 16; n++) acc[n] = fmaf(RL(fv[n], k), w, acc[n]);
      }
    }
    #pragma unroll
    for (int n = 0; n < 16; n++){
      int node = nodeBase + g0 + n;
      if (node < NN && degv[n] > 0.f) hidden[(size_t)node*64 + lane] += acc[n];
    }
  }
}

__global__ __launch_bounds__(256) void k_scoreK(const float* __restrict__ lw, const float* __restrict__ w1,
                                                const float* __restrict__ b1, const float* __restrict__ w2,
                                                const float* __restrict__ b2, const float* __restrict__ relb,
                                                const unsigned* __restrict__ dcnt,
                                                const float* __restrict__ hidden, float* __restrict__ score){
  int wid = threadIdx.x >> 6, lane = threadIdx.x & 63;
  int base = (blockIdx.x*4 + wid) * 8;
  if (base >= NN) return;
  float wreg[64];
  #pragma unroll
  for (int k = 0; k < 64; k++) wreg[k] = lw[k*64 + lane];
  float relbv = relb[lane];
  float hidv[8]; bool act[8];
  #pragma unroll
  for (int n = 0; n < 8; n++){
    int node = base + n;
    act[n] = (node < NN) && (dcnt[node] > 0u);
    hidv[n] = act[n] ? hidden[(size_t)node*64 + lane] : 0.f;
  }
  float hv[8];
  #pragma unroll
  for (int n = 0; n < 8; n++) hv[n] = relbv;
  #pragma unroll
  for (int k = 0; k < 64; k++){
    float w = wreg[k];
    #pragma unroll
    for (int n = 0; n < 8; n++) hv[n] = fmaf(RL(hidv[n], k), w, hv[n]);
  }
  float xv[8];
  #pragma unroll
  for (int n = 0; n < 8; n++) xv[n] = hidv[n] * hv[n];
  float outv[8];
  #pragma unroll
  for (int n = 0; n < 8; n++) outv[n] = 0.f;
  for (int half = 0; half < 2; half++){
    #pragma unroll
    for (int k = 0; k < 64; k++) wreg[k] = w1[k*128 + half*64 + lane];
    float a[8];
    float b1l = b1[half*64 + lane];
    #pragma unroll
    for (int n = 0; n < 8; n++) a[n] = b1l;
    #pragma unroll
    for (int k = 0; k < 64; k++){
      float w = wreg[k];
      #pragma unroll
      for (int n = 0; n < 8; n++) a[n] = fmaf(RL(xv[n], k), w, a[n]);
    }
    float w2l = w2[half*64 + lane];
    #pragma unroll
    for (int n = 0; n < 8; n++) outv[n] = fmaf(fmaxf(a[n], 0.f), w2l, outv[n]);
  }
  float b2v = b2[0];
  #pragma unroll
  for (int n = 0; n < 8; n++){
    float r = waveSumF(outv[n]);
    if (lane == 0 && act[n]) score[base + n] = r + b2v;
  }
}

__global__ void k_out(const int* __restrict__ t_index, const float* __restrict__ score,
                      float* __restrict__ out, int b){
  int t = threadIdx.x;
  if (t < NTC) out[b*NTC + t] = score[t_index[b*NTC + t]];
}

// ------------------------------- launcher -----------------------------------

extern "C" void kernel_launch(void* const* d_in, const int* in_sizes, int n_in,
                              void* d_out, int out_size, void* d_ws, size_t ws_size,
                              hipStream_t stream){
  (void)in_sizes; (void)n_in; (void)out_size; (void)ws_size;
  const int*   h_index  = (const int*)d_in[0];
  const int*   r_index  = (const int*)d_in[1];
  const int*   t_index  = (const int*)d_in[2];
  const int*   all_idx  = (const int*)d_in[3];
  const int*   esrc     = (const int*)d_in[4];
  const int*   edst     = (const int*)d_in[5];
  const int*   etype    = (const int*)d_in[6];
  const float* hs       = (const float*)d_in[7];
  const float* ste      = (const float*)d_in[8];
  const float* rel_tab  = (const float*)d_in[9];
  const float* lw       = (const float*)d_in[10];
  const float* lb       = (const float*)d_in[11];
  const float* w1       = (const float*)d_in[12];
  const float* b1       = (const float*)d_in[13];
  const float* w2       = (const float*)d_in[14];
  const float* b2       = (const float*)d_in[15];
  const float* relw     = (const float*)d_in[16];
  const float* pna_w    = (const float*)d_in[17];
  const float* pna_b    = (const float*)d_in[18];
  float* out = (float*)d_out;

  unsigned* W = (unsigned*)d_ws;
  // workspace layout (u32 units)
  unsigned* ST       = W + 0;          // 64
  float*    STF      = (float*)ST;
  unsigned* HIST     = W + 64;         // 65536
  float*    RELB     = (float*)(W + 65600);   // 64
  unsigned* BLOCKCNT = W + 65664;      // 2048
  int*      LASTM    = (int*)(W + 67712);     // 50000
  unsigned* NKEY     = W + 117712;     // 50000
  unsigned* NSEL     = W + 167712;     // 50000
  float*    SCORE    = (float*)(W + 217712);  // 50000
  unsigned* DCNT     = W + 267712;     // 50000
  unsigned* ROWS     = W + 317712;     // 50000
  unsigned* CURS     = W + 367712;     // 50000
  float*    HIDDEN   = (float*)(W + 417712);  // 3,200,000
  float*    SM       = (float*)(W + 3617712);
  float*    SQ       = (float*)(W + 6817712);
  float*    MX       = (float*)(W + 10017712);
  float*    MN       = (float*)(W + 13217712);
  unsigned* EKEY     = W + 16417712;   // 1,600,000
  unsigned* ELIST    = W + 18017712;   // 160,000
  unsigned* CSR      = W + 18177712;   // 160,000  (total 18,337,712 u32 = 73.4 MB)

  const int GB_E256  = (NEG + 255) / 256;     // 6250
  const int GB_N256  = (NN + 255) / 256;      // 196
  const int GB_N1024 = (NN + 1023) / 1024;    // 49
  const int GB_E1024 = (NEG + 1023) / 1024;   // 1563
  const int GB_H     = (NN * 64) / 256;       // 12500
  const int GB_SC    = (NN + 31) / 32;        // 1563
  const int GB_ES    = (int)(ESEL / 256);     // 625

  (void)hipMemsetAsync(ST, 0, 64 * 4, stream);
  (void)hipMemsetAsync(HIST, 0, 65536 * 4, stream);
  (void)hipMemsetAsync(LASTM, 0xFF, NN * 4, stream);
  (void)hipMemsetAsync(DCNT, 0, NN * 4, stream);

  k_lastm<<<(NMI + 255) / 256, 256, 0, stream>>>(all_idx, LASTM);
  k_degfull<<<GB_E256, 256, 0, stream>>>(esrc, DCNT);
  k_dsum<<<GB_N256, 256, 0, stream>>>(DCNT, STF);
  k_finalize<<<1, 1, 0, stream>>>(STF, b1, w2, b2);

  for (int b = 0; b < 4; b++){
    k_relb<<<1, 64, 0, stream>>>(r_index, hs, rel_tab, lw, lb, w1, b1, w2, b2, RELB, STF, b);
    k_inithidden<<<GB_H, 256, 0, stream>>>(LASTM, ste, hs, h_index, b, HIDDEN);
    k_initscore<<<GB_N256, 256, 0, stream>>>(h_index, b, STF, SCORE);

    for (int l = 0; l < 3; l++){
      // ---- node top-K
      k_nkey<<<GB_N256, 256, 0, stream>>>(SCORE, NKEY, ST);
      k_hist16<<<GB_N256, 256, 0, stream>>>(NKEY, NN, 1, ST, HIST);
      k_pick16<<<1, 1024, 0, stream>>>(1, ST, HIST);
      k_hist16<<<GB_N256, 256, 0, stream>>>(NKEY, NN, 0, ST, HIST);
      k_pick16<<<1, 1024, 0, stream>>>(0, ST, HIST);
      k_countEq<<<GB_N1024, 1024, 0, stream>>>(NKEY, NN, ST, BLOCKCNT);
      k_scanBlocks<<<1, 1024, 0, stream>>>(BLOCKCNT, GB_N1024);
      k_selNodes<<<GB_N1024, 1024, 0, stream>>>(NKEY, NN, ST, BLOCKCNT, NSEL);
      // ---- edge top-ESEL + compact (also zeroes DCNT)
      k_ekey<<<GB_E256, 256, 0, stream>>>(esrc, edst, NSEL, SCORE, EKEY, ST);
      k_hist16<<<GB_E256, 256, 0, stream>>>(EKEY, NEG, 1, ST, HIST);
      k_pick16<<<1, 1024, 0, stream>>>(1, ST, HIST);
      k_hist16<<<GB_E256, 256, 0, stream>>>(EKEY, NEG, 0, ST, HIST);
      k_pick16<<<1, 1024, 0, stream>>>(0, ST, HIST);
      k_countEq<<<GB_E1024, 1024, 0, stream>>>(EKEY, NEG, ST, BLOCKCNT);
      k_scanBlocks<<<1, 1024, 0, stream>>>(BLOCKCNT, GB_E1024);
      k_selEdgesCompact<<<GB_E1024, 1024, 0, stream>>>(EKEY, NEG, ST, BLOCKCNT, ELIST, DCNT);
      // ---- CSR by destination
      k_degcnt<<<GB_ES, 256, 0, stream>>>(ELIST, edst, ST, DCNT);
      k_blocksumsInt<<<GB_N1024, 1024, 0, stream>>>(DCNT, BLOCKCNT);
      k_scanBlocks<<<1, 1024, 0, stream>>>(BLOCKCNT, GB_N1024);
      k_rowstart<<<GB_N1024, 1024, 0, stream>>>(DCNT, BLOCKCNT, ROWS, CURS);
      k_scatter<<<GB_ES, 256, 0, stream>>>(ELIST, edst, ST, CURS, CSR);
      // ---- aggregate + PNA update + rescore
      k_aggcsr<<<GB_H, 256, 0, stream>>>(esrc, etype, CSR, ROWS, DCNT, SCORE, HIDDEN,
                                         relw + (size_t)l * NR2 * 64, SM, SQ, MX, MN);
      k_pna<<<GB_N256, 256, 0, stream>>>(pna_w + (size_t)l * 768 * 64, pna_b + (size_t)l * 64,
                                         SM, SQ, MX, MN, DCNT, STF, HIDDEN);
      k_scoreK<<<GB_SC, 256, 0, stream>>>(lw, w1, b1, w2, b2, RELB, DCNT, HIDDEN, SCORE);
    }
    k_out<<<1, 32, 0, stream>>>(t_index, SCORE, out, b);
  }
}

// Round 3
// 10823.634 us; speedup vs baseline: 1.5235x; 1.5235x over previous
//
#include <hip/hip_runtime.h>
#include <cstdint>
#include <cstddef>

// ---------------------------------------------------------------------------
// ConditionedPNA on MI355X, round 3.
// - 4 query batches folded into gridDim.y (one 3-layer pipeline, ~80 dispatches)
//   with automatic sequential fallback if d_ws is too small.
// - agg+PNA fused (stats in registers, 8 active nodes/wave) -> no stat arrays.
// - active-node compaction: PNA matmul + rescore only over deg>0 nodes.
// - hybrid histogram: 2 leader-aggregation rounds + scattered atomics.
// NOTE: all atomics use pointer-arithmetic form (arr + i) -- the source
// pipeline HTML-decodes "&"+identifier sequences.
// ---------------------------------------------------------------------------

#define NN   50000
#define NEG  1600000
#define NR2  1000
#define NTC  32
#define NMI  10000
#define KSEL 5000u
#define ESEL 160000u
#define KEY_NEG_INF 0x007FFFFFu

// per-batch workspace block offsets (u32 units)
#define OFF_ST    0         // 64
#define OFF_RELB  64        // 64
#define OFF_BC    128       // 2048
#define OFF_HIST  2176      // 65536
#define OFF_SCORE 67712     // 50000
#define OFF_NSEL  117712    // 50000
#define OFF_DCNT  167712    // 50000
#define OFF_ROWS  217712    // 50000
#define OFF_CURS  267712    // 50000
#define OFF_ACT   317712    // 50000
#define OFF_HID   367712    // 3200000
#define OFF_EKEY  3567712   // 1600000
#define OFF_ELIST 5167712   // 160000
#define OFF_CSR   5327712   // 160000
#define SBLK      5487712

#define RL(x,k) __int_as_float(__builtin_amdgcn_readlane(__float_as_int(x),(k)))
#define BBASE unsigned* B = WB + (size_t)blockIdx.y * (size_t)sb

__device__ inline unsigned fkey(float f){
  unsigned u = __float_as_uint(f);
  if ((u << 1) == 0u) u = 0u;                    // canonicalize -0 -> +0
  return (u & 0x80000000u) ? ~u : (u | 0x80000000u);
}

__device__ inline float waveSumF(float v){
  #pragma unroll
  for (int d = 1; d < 64; d <<= 1) v += __shfl_xor(v, d);
  return v;
}

__device__ inline unsigned getkey(const unsigned* B, int mode, int i){
  if (mode) return (B + OFF_EKEY)[i];
  return fkey(((const float*)(B + OFF_SCORE))[i]);
}

// ------------------------------- setup kernels ------------------------------

__global__ void k_lastm(const int* __restrict__ all_index, int* __restrict__ lastm){
  int i = blockIdx.x * 256 + threadIdx.x;
  if (i < NMI) atomicMax(lastm + all_index[i], i);
}

__global__ void k_degfull(const int* __restrict__ esrc, unsigned* __restrict__ degf){
  int i = blockIdx.x * 256 + threadIdx.x;
  if (i < NEG) atomicAdd(degf + esrc[i], 1u);
}

__global__ void k_dsum(const unsigned* __restrict__ degf, float* __restrict__ gstF){
  int i = blockIdx.x * 256 + threadIdx.x;
  float v = (i < NN) ? logf((float)degf[i] + 1.f) : 0.f;
  v = waveSumF(v);
  if ((threadIdx.x & 63) == 0) atomicAdd(gstF + 4, v);
}

__global__ void k_finalize(float* __restrict__ gstF, const float* __restrict__ b1,
                           const float* __restrict__ w2, const float* __restrict__ b2){
  gstF[5] = gstF[4] / (float)NN;                // dmean
  float s = 0.f;
  for (int m = 0; m < 128; m++) s += fmaxf(b1[m], 0.f) * w2[m];
  gstF[6] = s + b2[0];                          // base score for zero hidden
}

// ----------------------------- per-batch init -------------------------------

__global__ void k_relb(unsigned* WB, long sb, int b0,
                       const int* __restrict__ r_index, const float* __restrict__ hs,
                       const float* __restrict__ rel_table, const float* __restrict__ lw,
                       const float* __restrict__ lb, const float* __restrict__ w1,
                       const float* __restrict__ b1, const float* __restrict__ w2,
                       const float* __restrict__ b2){
  BBASE;
  float* relb = (float*)(B + OFF_RELB);
  float* stF  = (float*)(B + OFF_ST);
  int b = b0 + blockIdx.y;
  int j = threadIdx.x;                          // 64 threads, 1 wave
  int r = r_index[b];
  float acc = lb[j];
  for (int k = 0; k < 64; k++) acc = fmaf(rel_table[(size_t)r*64 + k], lw[(64 + k)*64 + j], acc);
  relb[j] = acc;
  float heur = acc;
  for (int k = 0; k < 64; k++) heur = fmaf(hs[b*64 + k], lw[k*64 + j], heur);
  float x = hs[b*64 + j] * heur;
  float o = 0.f;
  for (int half = 0; half < 2; half++){
    float a = b1[half*64 + j];
    for (int k = 0; k < 64; k++) a = fmaf(__shfl(x, k), w1[k*128 + half*64 + j], a);
    o = fmaf(fmaxf(a, 0.f), w2[half*64 + j], o);
  }
  o = waveSumF(o);
  if (j == 0) stF[7] = o + b2[0];
}

__global__ void k_inithidden(unsigned* WB, long sb, int b0,
                             const int* __restrict__ lastm, const float* __restrict__ ste,
                             const float* __restrict__ hs, const int* __restrict__ h_index){
  BBASE;
  float* hidden = (float*)(B + OFF_HID);
  int b = b0 + blockIdx.y;
  int idx = blockIdx.x * 256 + threadIdx.x;     // grid covers NN*64 exactly
  int n = idx >> 6, j = idx & 63;
  int h = h_index[b];
  float v = 0.f;
  int lm = lastm[n];
  if (lm >= 0) v = ste[(size_t)lm*64 + j];
  if (n == h)  v = hs[b*64 + j];
  hidden[idx] = v;
}

__global__ void k_initscore(unsigned* WB, long sb, int b0,
                            const int* __restrict__ h_index, const float* __restrict__ gstF){
  BBASE;
  float* score = (float*)(B + OFF_SCORE);
  unsigned* st = B + OFF_ST;
  float* stF = (float*)st;
  int b = b0 + blockIdx.y;
  int i = blockIdx.x * 256 + threadIdx.x;
  if (i < NN) score[i] = (i == h_index[b]) ? stF[7] : gstF[6];
  if (i == 0){ st[0] = 0u; st[1] = KSEL; }
}

// ------------------------------ top-k machinery -----------------------------

__global__ void k_ekey(unsigned* WB, long sb,
                       const int* __restrict__ esrc, const int* __restrict__ edst){
  BBASE;
  unsigned* st = B + OFF_ST;
  const unsigned* nsel = B + OFF_NSEL;
  const float* score = (const float*)(B + OFF_SCORE);
  unsigned* ekey = B + OFF_EKEY;
  int i = blockIdx.x * 256 + threadIdx.x;
  if (i < NEG) ekey[i] = nsel[esrc[i]] ? fkey(score[edst[i]]) : KEY_NEG_INF;
  if (i == 0){ st[0] = 0u; st[1] = ESEL; st[2] = 0u; st[3] = 0u; }
}

// hybrid histogram: 2 leader-aggregation rounds + scattered atomics
__global__ void k_hist(unsigned* WB, long sb, int pass, int mode, int n){
  BBASE;
  unsigned* st = B + OFF_ST;
  unsigned* hist = B + OFF_HIST;
  int i = blockIdx.x * 256 + threadIdx.x;
  unsigned bin = 0xFFFFFFFFu;
  if (i < n){
    unsigned k = getkey(B, mode, i);
    if (pass == 1) bin = k >> 16;
    else { if ((k >> 16) == (st[0] >> 16)) bin = k & 0xFFFFu; }
  }
  bool active = (bin != 0xFFFFFFFFu);
  int lane = threadIdx.x & 63;
  #pragma unroll
  for (int r = 0; r < 2; r++){
    unsigned long long mask = __ballot((int)active);
    if (mask != 0ull){
      int leader = __ffsll(mask) - 1;
      unsigned lbin = (unsigned)__shfl((int)bin, leader);
      bool same = active && (bin == lbin);
      unsigned long long smask = __ballot((int)same);
      if (lane == leader) atomicAdd(hist + lbin, (unsigned)__popcll(smask));
      if (same) active = false;
    }
  }
  if (active) atomicAdd(hist + bin, 1u);
}

// single block per batch: find digit containing the R-th largest; update st; zero hist
__global__ __launch_bounds__(1024) void k_pick16(unsigned* WB, long sb, int pass){
  BBASE;
  unsigned* st = B + OFF_ST;
  unsigned* hist = B + OFF_HIST;
  __shared__ unsigned csum[1024];
  __shared__ unsigned sc[1024];
  int t = threadIdx.x;
  unsigned R = st[1];
  unsigned s = 0;
  for (int b = 0; b < 64; b++) s += hist[t*64 + b];
  csum[t] = s; sc[t] = s; __syncthreads();
  for (int d = 1; d < 1024; d <<= 1){
    unsigned v = (t >= d) ? sc[t - d] : 0u;
    __syncthreads();
    sc[t] += v;
    __syncthreads();
  }
  unsigned total = sc[1023];
  unsigned above = total - sc[t];               // keys in higher chunks
  unsigned cs = csum[t];
  if (above < R && above + cs >= R){
    unsigned cum = above;
    for (int b = 63; b >= 0; b--){
      unsigned c = hist[t*64 + b];
      if (cum + c >= R){
        unsigned bstar = (unsigned)(t*64 + b);
        if (pass == 1) st[0] = bstar << 16; else st[0] = st[0] | bstar;
        st[1] = R - cum;
        break;
      }
      cum += c;
    }
  }
  for (int b = 0; b < 64; b++) hist[t*64 + b] = 0u;   // leave hist zeroed
}

__global__ __launch_bounds__(1024) void k_countEq(unsigned* WB, long sb, int mode, int n){
  BBASE;
  const unsigned* st = B + OFF_ST;
  unsigned* blockcnt = B + OFF_BC;
  int i = blockIdx.x * 1024 + threadIdx.x;
  unsigned v = st[0];
  bool eq = (i < n) && (getkey(B, mode, i) == v);
  unsigned long long bal = __ballot((int)eq);
  __shared__ unsigned wsh[16];
  int wid = threadIdx.x >> 6, lane = threadIdx.x & 63;
  if (lane == 0) wsh[wid] = (unsigned)__popcll(bal);
  __syncthreads();
  if (threadIdx.x == 0){
    unsigned tot = 0;
    for (int w = 0; w < 16; w++) tot += wsh[w];
    blockcnt[blockIdx.x] = tot;
  }
}

__global__ __launch_bounds__(1024) void k_scanBlocks(unsigned* WB, long sb, int nb){
  BBASE;
  unsigned* blockcnt = B + OFF_BC;
  __shared__ unsigned sc[2048];
  int t = threadIdx.x;
  unsigned a  = (t < nb) ? blockcnt[t] : 0u;
  unsigned b2 = (1024 + t < nb) ? blockcnt[1024 + t] : 0u;
  sc[t] = a; sc[1024 + t] = b2; __syncthreads();
  for (int d = 1; d < 2048; d <<= 1){
    unsigned v1 = (t >= d) ? sc[t - d] : 0u;
    unsigned v2 = (1024 + t >= d) ? sc[1024 + t - d] : 0u;
    __syncthreads();
    sc[t] += v1; sc[1024 + t] += v2;
    __syncthreads();
  }
  if (t < nb) blockcnt[t] = sc[t] - a;              // exclusive
  if (1024 + t < nb) blockcnt[1024 + t] = sc[1024 + t] - b2;
}

__global__ __launch_bounds__(1024) void k_selNodes(unsigned* WB, long sb){
  BBASE;
  const unsigned* st = B + OFF_ST;
  const unsigned* blockcnt = B + OFF_BC;
  unsigned* nsel = B + OFF_NSEL;
  int i = blockIdx.x * 1024 + threadIdx.x;
  unsigned v = st[0], R = st[1];
  unsigned k = (i < NN) ? getkey(B, 0, i) : 0u;
  bool eq = (i < NN) && (k == v);
  unsigned long long bal = __ballot((int)eq);
  __shared__ unsigned wsh[16];
  int wid = threadIdx.x >> 6, lane = threadIdx.x & 63;
  if (lane == 0) wsh[wid] = (unsigned)__popcll(bal);
  __syncthreads();
  unsigned woff = 0;
  for (int w = 0; w < wid; w++) woff += wsh[w];
  unsigned lpre = (unsigned)__popcll(bal & ((1ull << lane) - 1ull));
  unsigned rank = blockcnt[blockIdx.x] + woff + lpre;
  if (i < NN) nsel[i] = (k > v || (eq && rank < R)) ? 1u : 0u;
}

// select + compact valid edges; also zero DCNT for this layer
__global__ __launch_bounds__(1024) void k_selEdgesCompact(unsigned* WB, long sb){
  BBASE;
  unsigned* st = B + OFF_ST;
  const unsigned* blockcnt = B + OFF_BC;
  unsigned* elist = B + OFF_ELIST;
  unsigned* dcnt = B + OFF_DCNT;
  int i = blockIdx.x * 1024 + threadIdx.x;
  if (i < NN) dcnt[i] = 0u;
  unsigned v = st[0], R = st[1];
  unsigned k = (i < NEG) ? getkey(B, 1, i) : 0u;
  bool eq = (i < NEG) && (k == v);
  unsigned long long bal = __ballot((int)eq);
  __shared__ unsigned wsh[16];
  int wid = threadIdx.x >> 6, lane = threadIdx.x & 63;
  if (lane == 0) wsh[wid] = (unsigned)__popcll(bal);
  __syncthreads();
  unsigned woff = 0;
  for (int w = 0; w < wid; w++) woff += wsh[w];
  unsigned lpre = (unsigned)__popcll(bal & ((1ull << lane) - 1ull));
  unsigned rank = blockcnt[blockIdx.x] + woff + lpre;
  bool sel = (i < NEG) && (k > v || (eq && rank < R));
  bool take = sel && (k > KEY_NEG_INF);             // finite escore only
  unsigned long long m2 = __ballot((int)take);
  unsigned cnt = (unsigned)__popcll(m2);
  unsigned base = 0;
  if (lane == 0) base = atomicAdd(st + 2, cnt);
  base = (unsigned)__shfl((int)base, 0);
  if (take) elist[base + (unsigned)__popcll(m2 & ((1ull << lane) - 1ull))] = (unsigned)i;
}

// ------------------------------- CSR build ----------------------------------

__global__ void k_degcnt(unsigned* WB, long sb, const int* __restrict__ edst){
  BBASE;
  const unsigned* st = B + OFF_ST;
  const unsigned* elist = B + OFF_ELIST;
  unsigned* dcnt = B + OFF_DCNT;
  unsigned i = blockIdx.x * 256 + threadIdx.x;
  if (i < st[2]) atomicAdd(dcnt + edst[elist[i]], 1u);
}

__global__ __launch_bounds__(1024) void k_blocksumsInt(unsigned* WB, long sb){
  BBASE;
  const unsigned* dcnt = B + OFF_DCNT;
  unsigned* blockcnt = B + OFF_BC;
  int i = blockIdx.x * 1024 + threadIdx.x;
  unsigned v = (i < NN) ? dcnt[i] : 0u;
  #pragma unroll
  for (int d = 1; d < 64; d <<= 1) v += (unsigned)__shfl_xor((int)v, d);
  __shared__ unsigned wsh[16];
  int wid = threadIdx.x >> 6, lane = threadIdx.x & 63;
  if (lane == 0) wsh[wid] = v;
  __syncthreads();
  if (threadIdx.x == 0){
    unsigned tot = 0;
    for (int w = 0; w < 16; w++) tot += wsh[w];
    blockcnt[blockIdx.x] = tot;
  }
}

// row starts + cursor + ACTIVE list compaction
__global__ __launch_bounds__(1024) void k_rowstartAct(unsigned* WB, long sb){
  BBASE;
  unsigned* st = B + OFF_ST;
  const unsigned* dcnt = B + OFF_DCNT;
  const unsigned* blockcnt = B + OFF_BC;
  unsigned* rowstart = B + OFF_ROWS;
  unsigned* curs = B + OFF_CURS;
  unsigned* actl = B + OFF_ACT;
  int i = blockIdx.x * 1024 + threadIdx.x;
  int wid = threadIdx.x >> 6, lane = threadIdx.x & 63;
  unsigned d = (i < NN) ? dcnt[i] : 0u;
  unsigned v = d;
  #pragma unroll
  for (int dl = 1; dl < 64; dl <<= 1){
    unsigned t2 = (unsigned)__shfl_up((int)v, dl);
    if (lane >= dl) v += t2;
  }
  __shared__ unsigned wsh[16];
  if (lane == 63) wsh[wid] = v;
  __syncthreads();
  unsigned woff = 0;
  for (int w = 0; w < wid; w++) woff += wsh[w];
  unsigned excl = blockcnt[blockIdx.x] + woff + (v - d);
  if (i < NN){
    rowstart[i] = excl; curs[i] = excl;
    if (d > 0u){ unsigned p = atomicAdd(st + 3, 1u); actl[p] = (unsigned)i; }
  }
}

__global__ void k_scatter(unsigned* WB, long sb, const int* __restrict__ edst){
  BBASE;
  const unsigned* st = B + OFF_ST;
  const unsigned* elist = B + OFF_ELIST;
  unsigned* curs = B + OFF_CURS;
  unsigned* csr = B + OFF_CSR;
  unsigned i = blockIdx.x * 256 + threadIdx.x;
  if (i < st[2]){
    unsigned e = elist[i];
    unsigned pos = atomicAdd(curs + edst[e], 1u);
    csr[pos] = e;
  }
}

// --------------------- fused aggregation + PNA update -----------------------

__global__ __launch_bounds__(256) void k_aggpna(unsigned* WB, long sb,
    const int* __restrict__ esrc, const int* __restrict__ etype,
    const float* __restrict__ relw, const float* __restrict__ pw,
    const float* __restrict__ pb, const float* __restrict__ gstF, int l){
  BBASE;
  const unsigned* st = B + OFF_ST;
  const unsigned* actl = B + OFF_ACT;
  const unsigned* dcnt = B + OFF_DCNT;
  const unsigned* rows = B + OFF_ROWS;
  const unsigned* csr = B + OFF_CSR;
  const float* score = (const float*)(B + OFF_SCORE);
  float* hidden = (float*)(B + OFF_HID);
  const float* relw_l = relw + (size_t)l * NR2 * 64;
  const float* pw_l = pw + (size_t)l * 768 * 64;

  int wv = (blockIdx.x * 256 + threadIdx.x) >> 6;
  int lane = threadIdx.x & 63;
  unsigned nact = st[3];
  unsigned slot0 = (unsigned)wv * 8u;
  if (slot0 >= nact) return;

  int node[8]; float degv[8];
  float smv[8], sqv[8], mxv[8], mnv[8];
  #pragma unroll
  for (int n = 0; n < 8; n++){
    unsigned s = slot0 + (unsigned)n;
    node[n] = (s < nact) ? (int)actl[s] : -1;
  }
  #pragma unroll
  for (int n = 0; n < 8; n++){
    float sm_ = 0.f, sq_ = 0.f;
    float mx_ = -__builtin_huge_valf(), mn_ = __builtin_huge_valf();
    float dv = 0.f;
    if (node[n] >= 0){
      unsigned cnt = dcnt[node[n]], rs = rows[node[n]];
      dv = (float)cnt;
      for (unsigned ii = 0; ii < cnt; ii++){
        int e = (int)csr[rs + ii];
        int s = esrc[e], t = etype[e];
        float g = 1.f / (1.f + expf(-score[s]));
        float m = g * hidden[(size_t)s*64 + lane] * relw_l[(size_t)t*64 + lane];
        sm_ += m; sq_ = fmaf(m, m, sq_);
        mx_ = fmaxf(mx_, m); mn_ = fminf(mn_, m);
      }
    }
    smv[n] = sm_; sqv[n] = sq_; mxv[n] = mx_; mnv[n] = mn_; degv[n] = dv;
  }
  float dmean = gstF[5];
  float bias = pb[(size_t)l*64 + lane];
  float acc[8];
  #pragma unroll
  for (int n = 0; n < 8; n++) acc[n] = bias;
  for (int c = 0; c < 12; c++){
    int a = c / 3, s = c - a*3;
    float wreg[64];
    #pragma unroll
    for (int k = 0; k < 64; k++) wreg[k] = pw_l[(size_t)(c*64 + k)*64 + lane];
    float fv[8];
    #pragma unroll
    for (int n = 0; n < 8; n++){
      float v = 0.f;
      if (node[n] >= 0){
        float degc = fmaxf(degv[n], 1.f);
        float logd = logf(degv[n] + 1.f);
        float scaler = (s == 0) ? 1.f : ((s == 1) ? (logd / dmean) : (dmean / fmaxf(logd, 1e-6f)));
        if (a == 0)      v = smv[n] / degc;
        else if (a == 1) v = mxv[n];
        else if (a == 2) v = mnv[n];
        else { float me = smv[n] / degc; float qv = sqv[n] / degc;
               v = sqrtf(fmaxf(qv - me*me, 0.f) + 1e-6f); }
        v *= scaler;
      }
      fv[n] = v;
    }
    #pragma unroll
    for (int k = 0; k < 64; k++){
      float w = wreg[k];
      #pragma unroll
      for (int n = 0; n < 8; n++) acc[n] = fmaf(RL(fv[n], k), w, acc[n]);
    }
  }
  #pragma unroll
  for (int n = 0; n < 8; n++)
    if (node[n] >= 0) hidden[(size_t)node[n]*64 + lane] += acc[n];
}

// ------------------------- rescore active nodes -----------------------------

__global__ __launch_bounds__(256) void k_scoreK(unsigned* WB, long sb,
    const float* __restrict__ lw, const float* __restrict__ w1,
    const float* __restrict__ b1, const float* __restrict__ w2,
    const float* __restrict__ b2){
  BBASE;
  unsigned* st = B + OFF_ST;
  if (blockIdx.x == 0 && threadIdx.x == 0){ st[0] = 0u; st[1] = KSEL; }  // next layer's node topk
  const unsigned* actl = B + OFF_ACT;
  const float* hidden = (const float*)(B + OFF_HID);
  const float* relb = (const float*)(B + OFF_RELB);
  float* score = (float*)(B + OFF_SCORE);
  unsigned nact = st[3];
  int wv = (blockIdx.x * 256 + threadIdx.x) >> 6;
  int lane = threadIdx.x & 63;
  unsigned slot0 = (unsigned)wv * 8u;
  if (slot0 >= nact) return;
  int node[8];
  #pragma unroll
  for (int n = 0; n < 8; n++){
    unsigned s = slot0 + (unsigned)n;
    node[n] = (s < nact) ? (int)actl[s] : -1;
  }
  float wreg[64];
  #pragma unroll
  for (int k = 0; k < 64; k++) wreg[k] = lw[k*64 + lane];
  float relbv = relb[lane];
  float hidv[8];
  #pragma unroll
  for (int n = 0; n < 8; n++)
    hidv[n] = (node[n] >= 0) ? hidden[(size_t)node[n]*64 + lane] : 0.f;
  float hv[8];
  #pragma unroll
  for (int n = 0; n < 8; n++) hv[n] = relbv;
  #pragma unroll
  for (int k = 0; k < 64; k++){
    float w = wreg[k];
    #pragma unroll
    for (int n = 0; n < 8; n++) hv[n] = fmaf(RL(hidv[n], k), w, hv[n]);
  }
  float xv[8];
  #pragma unroll
  for (int n = 0; n < 8; n++) xv[n] = hidv[n] * hv[n];
  float outv[8];
  #pragma unroll
  for (int n = 0; n < 8; n++) outv[n] = 0.f;
  for (int half = 0; half < 2; half++){
    #pragma unroll
    for (int k = 0; k < 64; k++) wreg[k] = w1[k*128 + half*64 + lane];
    float a[8];
    float b1l = b1[half*64 + lane];
    #pragma unroll
    for (int n = 0; n < 8; n++) a[n] = b1l;
    #pragma unroll
    for (int k = 0; k < 64; k++){
      float w = wreg[k];
      #pragma unroll
      for (int n = 0; n < 8; n++) a[n] = fmaf(RL(xv[n], k), w, a[n]);
    }
    float w2l = w2[half*64 + lane];
    #pragma unroll
    for (int n = 0; n < 8; n++) outv[n] = fmaf(fmaxf(a[n], 0.f), w2l, outv[n]);
  }
  float b2v = b2[0];
  #pragma unroll
  for (int n = 0; n < 8; n++){
    float r = waveSumF(outv[n]);
    if (lane == 0 && node[n] >= 0) score[node[n]] = r + b2v;
  }
}

__global__ void k_out(unsigned* WB, long sb, int b0,
                      const int* __restrict__ t_index, float* __restrict__ out){
  BBASE;
  const float* score = (const float*)(B + OFF_SCORE);
  int b = b0 + blockIdx.y;
  int t = threadIdx.x;
  if (t < NTC) out[b*NTC + t] = score[t_index[b*NTC + t]];
}

// ------------------------------- launcher -----------------------------------

extern "C" void kernel_launch(void* const* d_in, const int* in_sizes, int n_in,
                              void* d_out, int out_size, void* d_ws, size_t ws_size,
                              hipStream_t stream){
  (void)in_sizes; (void)n_in; (void)out_size;
  const int*   h_index  = (const int*)d_in[0];
  const int*   r_index  = (const int*)d_in[1];
  const int*   t_index  = (const int*)d_in[2];
  const int*   all_idx  = (const int*)d_in[3];
  const int*   esrc     = (const int*)d_in[4];
  const int*   edst     = (const int*)d_in[5];
  const int*   etype    = (const int*)d_in[6];
  const float* hs       = (const float*)d_in[7];
  const float* ste      = (const float*)d_in[8];
  const float* rel_tab  = (const float*)d_in[9];
  const float* lw       = (const float*)d_in[10];
  const float* lb       = (const float*)d_in[11];
  const float* w1       = (const float*)d_in[12];
  const float* b1       = (const float*)d_in[13];
  const float* w2       = (const float*)d_in[14];
  const float* b2       = (const float*)d_in[15];
  const float* relw     = (const float*)d_in[16];
  const float* pna_w    = (const float*)d_in[17];
  const float* pna_b    = (const float*)d_in[18];
  float* out = (float*)d_out;

  unsigned* W = (unsigned*)d_ws;
  int*      LASTM = (int*)W;                    // 50000
  unsigned* DEGF  = W + 50000;                  // 50000
  float*    GSTF  = (float*)(W + 100000);       // 64
  unsigned* WB    = W + 100064;                 // batch blocks

  size_t needB = (size_t)(100064 + 4*(size_t)SBLK) * 4u;
  int nb; long sb; int nseq;
  if (ws_size >= needB){ nb = 4; sb = SBLK; nseq = 1; }
  else                 { nb = 1; sb = 0;    nseq = 4; }

  (void)hipMemsetAsync(W + 100000, 0, 64 * 4, stream);          // GSTF
  (void)hipMemsetAsync(LASTM, 0xFF, NN * 4, stream);
  (void)hipMemsetAsync(DEGF, 0, NN * 4, stream);
  for (int q = 0; q < nb; q++)
    (void)hipMemsetAsync(WB + (size_t)q*SBLK + OFF_HIST, 0, 65536 * 4, stream);

  const int GB_E256  = (NEG + 255) / 256;       // 6250
  const int GB_N256  = (NN + 255) / 256;        // 196
  const int GB_N1024 = (NN + 1023) / 1024;      // 49
  const int GB_E1024 = (NEG + 1023) / 1024;     // 1563
  const int GB_H     = (NN * 64) / 256;         // 12500
  const int GB_A     = 1563;                    // 4 waves x 8 slots covers 50016
  const int GB_ES    = (int)(ESEL / 256);       // 625

  k_lastm<<<(NMI + 255) / 256, 256, 0, stream>>>(all_idx, LASTM);
  k_degfull<<<GB_E256, 256, 0, stream>>>(esrc, DEGF);
  k_dsum<<<GB_N256, 256, 0, stream>>>(DEGF, GSTF);
  k_finalize<<<1, 1, 0, stream>>>(GSTF, b1, w2, b2);

  for (int q = 0; q < nseq; q++){
    int b0 = (nb == 4) ? 0 : q;
    k_relb<<<dim3(1, nb), 64, 0, stream>>>(WB, sb, b0, r_index, hs, rel_tab, lw, lb, w1, b1, w2, b2);
    k_inithidden<<<dim3(GB_H, nb), 256, 0, stream>>>(WB, sb, b0, LASTM, ste, hs, h_index);
    k_initscore<<<dim3(GB_N256, nb), 256, 0, stream>>>(WB, sb, b0, h_index, GSTF);

    for (int l = 0; l < 3; l++){
      // ---- node top-K
      k_hist<<<dim3(GB_N256, nb), 256, 0, stream>>>(WB, sb, 1, 0, NN);
      k_pick16<<<dim3(1, nb), 1024, 0, stream>>>(WB, sb, 1);
      k_hist<<<dim3(GB_N256, nb), 256, 0, stream>>>(WB, sb, 0, 0, NN);
      k_pick16<<<dim3(1, nb), 1024, 0, stream>>>(WB, sb, 0);
      k_countEq<<<dim3(GB_N1024, nb), 1024, 0, stream>>>(WB, sb, 0, NN);
      k_scanBlocks<<<dim3(1, nb), 1024, 0, stream>>>(WB, sb, GB_N1024);
      k_selNodes<<<dim3(GB_N1024, nb), 1024, 0, stream>>>(WB, sb);
      // ---- edge top-ESEL + compact
      k_ekey<<<dim3(GB_E256, nb), 256, 0, stream>>>(WB, sb, esrc, edst);
      k_hist<<<dim3(GB_E256, nb), 256, 0, stream>>>(WB, sb, 1, 1, NEG);
      k_pick16<<<dim3(1, nb), 1024, 0, stream>>>(WB, sb, 1);
      k_hist<<<dim3(GB_E256, nb), 256, 0, stream>>>(WB, sb, 0, 1, NEG);
      k_pick16<<<dim3(1, nb), 1024, 0, stream>>>(WB, sb, 0);
      k_countEq<<<dim3(GB_E1024, nb), 1024, 0, stream>>>(WB, sb, 1, NEG);
      k_scanBlocks<<<dim3(1, nb), 1024, 0, stream>>>(WB, sb, GB_E1024);
      k_selEdgesCompact<<<dim3(GB_E1024, nb), 1024, 0, stream>>>(WB, sb);
      // ---- CSR by destination + active compaction
      k_degcnt<<<dim3(GB_ES, nb), 256, 0, stream>>>(WB, sb, edst);
      k_blocksumsInt<<<dim3(GB_N1024, nb), 1024, 0, stream>>>(WB, sb);
      k_scanBlocks<<<dim3(1, nb), 1024, 0, stream>>>(WB, sb, GB_N1024);
      k_rowstartAct<<<dim3(GB_N1024, nb), 1024, 0, stream>>>(WB, sb);
      k_scatter<<<dim3(GB_ES, nb), 256, 0, stream>>>(WB, sb, edst);
      // ---- fused aggregate + PNA update, then rescore
      k_aggpna<<<dim3(GB_A, nb), 256, 0, stream>>>(WB, sb, esrc, etype, relw, pna_w, pna_b, GSTF, l);
      k_scoreK<<<dim3(GB_A, nb), 256, 0, stream>>>(WB, sb, lw, w1, b1, w2, b2);
    }
    k_out<<<dim3(1, nb), 32, 0, stream>>>(WB, sb, b0, t_index, out);
  }
}

// Round 7
// 5012.819 us; speedup vs baseline: 3.2896x; 2.1592x over previous
//
#include <hip/hip_runtime.h>
#include <cstdint>
#include <cstddef>

// ---------------------------------------------------------------------------
// ConditionedPNA on MI355X, round 7.
// = round-4 kernel (5.0 ms infra: batched grid.y, fused agg+PNA, scan-based
// edge compaction, LDS-hash + 8-plane histogram, neg-inf skip) with ONE
// floating-point reversion: dmean is computed exactly as in the PASSING
// round-2/3 kernels (per-wave f32 atomicAdd, hardware order) — the serial
// dmean sum introduced in round 4 was the only fp change R3->R4 and moved
// the output 0.008 -> 0.02-0.03 vs reference. All other fp chains are
// identical to the validated R3 kernel.
// NOTE: all atomics use pointer-arithmetic form (arr + i) -- the source
// pipeline HTML-decodes "&"+identifier sequences.
// ---------------------------------------------------------------------------

#define NN   50000
#define NEG  1600000
#define NR2  1000
#define NTC  32
#define NMI  10000
#define KSEL 5000u
#define ESEL 160000u
#define KEY_NEG_INF 0x007FFFFFu
#define NRHIST 8

// per-batch workspace block offsets (u32 units)
#define OFF_ST    0         // 64   (st[0]=v st[1]=R st[2]=takeTot st[3]=nact st[4]=gtTot, stF[7]=head score)
#define OFF_RELB  64        // 64
#define OFF_BC    128       // 2048
#define OFF_BC2   2176      // 2048
#define OFF_HIST  4224      // 65536*8 = 524288
#define OFF_SCORE 528512    // 50000
#define OFF_NSEL  578512    // 50000
#define OFF_DCNT  628512    // 50000
#define OFF_ROWS  678512    // 50000
#define OFF_CURS  728512    // 50000
#define OFF_ACT   778512    // 50000
#define OFF_HID   828512    // 3200000
#define OFF_EKEY  4028512   // 1600000
#define OFF_ELIST 5628512   // 160000
#define OFF_CSR   5788512   // 160000
#define SBLK      5948512

#define RL(x,k) __int_as_float(__builtin_amdgcn_readlane(__float_as_int(x),(k)))
#define BBASE unsigned* B = WB + (size_t)blockIdx.y * (size_t)sb

__device__ inline unsigned fkey(float f){
  unsigned u = __float_as_uint(f);
  if ((u << 1) == 0u) u = 0u;                    // canonicalize -0 -> +0
  return (u & 0x80000000u) ? ~u : (u | 0x80000000u);
}

__device__ inline float waveSumF(float v){
  #pragma unroll
  for (int d = 1; d < 64; d <<= 1) v += __shfl_xor(v, d);
  return v;
}

__device__ inline unsigned getkey(const unsigned* B, int mode, int i){
  if (mode) return (B + OFF_EKEY)[i];
  return fkey(((const float*)(B + OFF_SCORE))[i]);
}

__device__ inline void ldsHashAdd(unsigned* hkey, unsigned* hval, unsigned bin, unsigned cnt){
  unsigned h = (bin * 2654435761u) >> 23;        // 9 bits -> 0..511
  while (true){
    unsigned prev = atomicCAS(hkey + h, 0xFFFFFFFFu, bin);
    if (prev == 0xFFFFFFFFu || prev == bin){ atomicAdd(hval + h, cnt); return; }
    h = (h + 1u) & 511u;
  }
}

// ------------------------------- setup kernels ------------------------------

__global__ void k_lastm(const int* __restrict__ all_index, int* __restrict__ lastm){
  int i = blockIdx.x * 256 + threadIdx.x;
  if (i < NMI) atomicMax(lastm + all_index[i], i);
}

__global__ void k_degfull(const int* __restrict__ esrc, unsigned* __restrict__ degf){
  int i = blockIdx.x * 256 + threadIdx.x;
  if (i < NEG) atomicAdd(degf + esrc[i], 1u);
}

// dmean accumulation: per-wave f32 atomicAdd, hardware order (validated R2/R3)
__global__ void k_dsum(const unsigned* __restrict__ degf, float* __restrict__ gstF){
  int i = blockIdx.x * 256 + threadIdx.x;
  float v = (i < NN) ? logf((float)degf[i] + 1.f) : 0.f;
  v = waveSumF(v);
  if ((threadIdx.x & 63) == 0) atomicAdd(gstF + 4, v);
}

__global__ void k_finalize(float* __restrict__ gstF, const float* __restrict__ b1,
                           const float* __restrict__ w2, const float* __restrict__ b2){
  gstF[5] = gstF[4] / (float)NN;                // dmean
  float s = 0.f;
  for (int m = 0; m < 128; m++) s += fmaxf(b1[m], 0.f) * w2[m];
  gstF[6] = s + b2[0];                          // base score for zero hidden
}

// ----------------------------- per-batch init -------------------------------

__global__ void k_relb(unsigned* WB, long sb, int b0,
                       const int* __restrict__ r_index, const float* __restrict__ hs,
                       const float* __restrict__ rel_table, const float* __restrict__ lw,
                       const float* __restrict__ lb, const float* __restrict__ w1,
                       const float* __restrict__ b1, const float* __restrict__ w2,
                       const float* __restrict__ b2){
  BBASE;
  float* relb = (float*)(B + OFF_RELB);
  float* stF  = (float*)(B + OFF_ST);
  int b = b0 + blockIdx.y;
  int j = threadIdx.x;                          // 64 threads, 1 wave
  int r = r_index[b];
  float acc = lb[j];
  for (int k = 0; k < 64; k++) acc = fmaf(rel_table[(size_t)r*64 + k], lw[(64 + k)*64 + j], acc);
  relb[j] = acc;
  float heur = acc;
  for (int k = 0; k < 64; k++) heur = fmaf(hs[b*64 + k], lw[k*64 + j], heur);
  float x = hs[b*64 + j] * heur;
  float o = 0.f;
  for (int half = 0; half < 2; half++){
    float a = b1[half*64 + j];
    for (int k = 0; k < 64; k++) a = fmaf(__shfl(x, k), w1[k*128 + half*64 + j], a);
    o = fmaf(fmaxf(a, 0.f), w2[half*64 + j], o);
  }
  o = waveSumF(o);
  if (j == 0) stF[7] = o + b2[0];
}

__global__ void k_inithidden(unsigned* WB, long sb, int b0,
                             const int* __restrict__ lastm, const float* __restrict__ ste,
                             const float* __restrict__ hs, const int* __restrict__ h_index){
  BBASE;
  float* hidden = (float*)(B + OFF_HID);
  int b = b0 + blockIdx.y;
  int idx = blockIdx.x * 256 + threadIdx.x;     // grid covers NN*64 exactly
  int n = idx >> 6, j = idx & 63;
  int h = h_index[b];
  float v = 0.f;
  int lm = lastm[n];
  if (lm >= 0) v = ste[(size_t)lm*64 + j];
  if (n == h)  v = hs[b*64 + j];
  hidden[idx] = v;
}

__global__ void k_initscore(unsigned* WB, long sb, int b0,
                            const int* __restrict__ h_index, const float* __restrict__ gstF){
  BBASE;
  float* score = (float*)(B + OFF_SCORE);
  unsigned* st = B + OFF_ST;
  float* stF = (float*)st;
  int b = b0 + blockIdx.y;
  int i = blockIdx.x * 256 + threadIdx.x;
  if (i < NN) score[i] = (i == h_index[b]) ? stF[7] : gstF[6];
  if (i == 0){ st[0] = 0u; st[1] = KSEL; }
}

// ------------------------------ top-k machinery -----------------------------

__global__ void k_ekey(unsigned* WB, long sb,
                       const int* __restrict__ esrc, const int* __restrict__ edst){
  BBASE;
  unsigned* st = B + OFF_ST;
  const unsigned* nsel = B + OFF_NSEL;
  const float* score = (const float*)(B + OFF_SCORE);
  unsigned* ekey = B + OFF_EKEY;
  int i = blockIdx.x * 256 + threadIdx.x;
  if (i < NEG) ekey[i] = nsel[esrc[i]] ? fkey(score[edst[i]]) : KEY_NEG_INF;
  if (i == 0){ st[0] = 0u; st[1] = ESEL; st[2] = 0u; st[3] = 0u; st[4] = 0u; }
}

// histogram: skip KEY_NEG_INF; 2 leader rounds -> LDS hash -> replicated flush
__global__ __launch_bounds__(256) void k_hist(unsigned* WB, long sb, int pass, int mode, int n){
  BBASE;
  const unsigned* st = B + OFF_ST;
  unsigned* hist = B + OFF_HIST;
  __shared__ unsigned hkey[512];
  __shared__ unsigned hval[512];
  for (int t = threadIdx.x; t < 512; t += 256){ hkey[t] = 0xFFFFFFFFu; hval[t] = 0u; }
  __syncthreads();
  int i = blockIdx.x * 256 + threadIdx.x;
  unsigned bin = 0xFFFFFFFFu;
  if (i < n){
    unsigned k = getkey(B, mode, i);
    if (k != KEY_NEG_INF){
      if (pass == 1) bin = k >> 16;
      else if ((k >> 16) == (st[0] >> 16)) bin = k & 0xFFFFu;
    }
  }
  bool active = (bin != 0xFFFFFFFFu);
  int lane = threadIdx.x & 63;
  #pragma unroll
  for (int r = 0; r < 2; r++){
    unsigned long long mask = __ballot((int)active);
    if (mask != 0ull){
      int leader = __ffsll(mask) - 1;
      unsigned lbin = (unsigned)__shfl((int)bin, leader);
      bool same = active && (bin == lbin);
      unsigned long long smask = __ballot((int)same);
      if (lane == leader) ldsHashAdd(hkey, hval, lbin, (unsigned)__popcll(smask));
      if (same) active = false;
    }
  }
  if (active) ldsHashAdd(hkey, hval, bin, 1u);
  __syncthreads();
  unsigned rep = (unsigned)blockIdx.x & (NRHIST - 1u);
  for (int t = threadIdx.x; t < 512; t += 256){
    unsigned vv = hval[t];
    if (vv) atomicAdd(hist + (size_t)rep * 65536u + hkey[t], vv);
  }
}

// single block per batch: find digit containing the R-th largest; update st; zero hist
__global__ __launch_bounds__(1024) void k_pick16(unsigned* WB, long sb, int pass){
  BBASE;
  unsigned* st = B + OFF_ST;
  unsigned* hist = B + OFF_HIST;
  __shared__ unsigned csum[1024];
  __shared__ unsigned sc[1024];
  int t = threadIdx.x;
  unsigned R = st[1];
  unsigned s = 0;
  for (int r = 0; r < NRHIST; r++){
    const unsigned* hp = hist + (size_t)r * 65536u + (unsigned)t * 64u;
    for (int b = 0; b < 64; b++) s += hp[b];
  }
  csum[t] = s; sc[t] = s; __syncthreads();
  for (int d = 1; d < 1024; d <<= 1){
    unsigned v = (t >= d) ? sc[t - d] : 0u;
    __syncthreads();
    sc[t] += v;
    __syncthreads();
  }
  unsigned total = sc[1023];
  unsigned above = total - sc[t];               // keys in higher chunks
  unsigned cs = csum[t];
  if (above < R && above + cs >= R){
    unsigned cum = above;
    for (int b = 63; b >= 0; b--){
      unsigned c = 0;
      for (int r = 0; r < NRHIST; r++) c += hist[(size_t)r * 65536u + (unsigned)(t*64 + b)];
      if (cum + c >= R){
        unsigned bstar = (unsigned)(t*64 + b);
        if (pass == 1) st[0] = bstar << 16; else st[0] = st[0] | bstar;
        st[1] = R - cum;
        break;
      }
      cum += c;
    }
  }
  if (t == 0 && total < R){                     // threshold lands in -inf bin
    if (pass == 1) st[0] = KEY_NEG_INF & 0xFFFF0000u;
    else           st[0] = st[0] | 0xFFFFu;
    st[1] = R - total;
  }
  for (int r = 0; r < NRHIST; r++){
    unsigned* hp = hist + (size_t)r * 65536u + (unsigned)t * 64u;
    for (int b = 0; b < 64; b++) hp[b] = 0u;    // leave hist zeroed
  }
}

// per-block counts of (eq, gt) vs threshold
__global__ __launch_bounds__(1024) void k_countEq(unsigned* WB, long sb, int mode, int n){
  BBASE;
  const unsigned* st = B + OFF_ST;
  unsigned* bcE = B + OFF_BC;
  unsigned* bcG = B + OFF_BC2;
  int i = blockIdx.x * 1024 + threadIdx.x;
  unsigned v = st[0];
  unsigned k = (i < n) ? getkey(B, mode, i) : 0u;
  bool eq = (i < n) && (k == v);
  bool gt = (i < n) && (k > v);
  unsigned long long ebal = __ballot((int)eq);
  unsigned long long gbal = __ballot((int)gt);
  __shared__ unsigned wshE[16];
  __shared__ unsigned wshG[16];
  int wid = threadIdx.x >> 6, lane = threadIdx.x & 63;
  if (lane == 0){ wshE[wid] = (unsigned)__popcll(ebal); wshG[wid] = (unsigned)__popcll(gbal); }
  __syncthreads();
  if (threadIdx.x == 0){
    unsigned te = 0, tg = 0;
    for (int w = 0; w < 16; w++){ te += wshE[w]; tg += wshG[w]; }
    bcE[blockIdx.x] = te; bcG[blockIdx.x] = tg;
  }
}

__global__ __launch_bounds__(1024) void k_scanBlocks(unsigned* WB, long sb, int nbk){
  BBASE;
  unsigned* blockcnt = B + OFF_BC;
  __shared__ unsigned sc[2048];
  int t = threadIdx.x;
  unsigned a  = (t < nbk) ? blockcnt[t] : 0u;
  unsigned b2 = (1024 + t < nbk) ? blockcnt[1024 + t] : 0u;
  sc[t] = a; sc[1024 + t] = b2; __syncthreads();
  for (int d = 1; d < 2048; d <<= 1){
    unsigned v1 = (t >= d) ? sc[t - d] : 0u;
    unsigned v2 = (1024 + t >= d) ? sc[1024 + t - d] : 0u;
    __syncthreads();
    sc[t] += v1; sc[1024 + t] += v2;
    __syncthreads();
  }
  if (t < nbk) blockcnt[t] = sc[t] - a;             // exclusive
  if (1024 + t < nbk) blockcnt[1024 + t] = sc[1024 + t] - b2;
}

// dual scan (eq + gt) for edge compaction; also computes st[2], st[4]
__global__ __launch_bounds__(1024) void k_scanBlocks2(unsigned* WB, long sb, int nbk){
  BBASE;
  unsigned* st = B + OFF_ST;
  unsigned* bcE = B + OFF_BC;
  unsigned* bcG = B + OFF_BC2;
  __shared__ unsigned se[2048];
  __shared__ unsigned sg[2048];
  int t = threadIdx.x;
  unsigned e0 = (t < nbk) ? bcE[t] : 0u;
  unsigned e1 = (1024 + t < nbk) ? bcE[1024 + t] : 0u;
  unsigned g0 = (t < nbk) ? bcG[t] : 0u;
  unsigned g1 = (1024 + t < nbk) ? bcG[1024 + t] : 0u;
  se[t] = e0; se[1024 + t] = e1; sg[t] = g0; sg[1024 + t] = g1;
  __syncthreads();
  for (int d = 1; d < 2048; d <<= 1){
    unsigned a1 = (t >= d) ? se[t - d] : 0u;
    unsigned a2 = (1024 + t >= d) ? se[1024 + t - d] : 0u;
    unsigned c1 = (t >= d) ? sg[t - d] : 0u;
    unsigned c2 = (1024 + t >= d) ? sg[1024 + t - d] : 0u;
    __syncthreads();
    se[t] += a1; se[1024 + t] += a2; sg[t] += c1; sg[1024 + t] += c2;
    __syncthreads();
  }
  if (t < nbk) bcE[t] = se[t] - e0;
  if (1024 + t < nbk) bcE[1024 + t] = se[1024 + t] - e1;
  if (t < nbk) bcG[t] = sg[t] - g0;
  if (1024 + t < nbk) bcG[1024 + t] = sg[1024 + t] - g1;
  if (t == 0){
    unsigned gtTot = sg[2047];
    st[4] = gtTot;
    st[2] = gtTot + ((st[0] > KEY_NEG_INF) ? st[1] : 0u);  // R' <= eqTot always
  }
}

__global__ __launch_bounds__(1024) void k_selNodes(unsigned* WB, long sb){
  BBASE;
  const unsigned* st = B + OFF_ST;
  const unsigned* blockcnt = B + OFF_BC;
  unsigned* nsel = B + OFF_NSEL;
  int i = blockIdx.x * 1024 + threadIdx.x;
  unsigned v = st[0], R = st[1];
  unsigned k = (i < NN) ? getkey(B, 0, i) : 0u;
  bool eq = (i < NN) && (k == v);
  unsigned long long bal = __ballot((int)eq);
  __shared__ unsigned wsh[16];
  int wid = threadIdx.x >> 6, lane = threadIdx.x & 63;
  if (lane == 0) wsh[wid] = (unsigned)__popcll(bal);
  __syncthreads();
  unsigned woff = 0;
  for (int w = 0; w < wid; w++) woff += wsh[w];
  unsigned lpre = (unsigned)__popcll(bal & ((1ull << lane) - 1ull));
  unsigned rank = blockcnt[blockIdx.x] + woff + lpre;
  if (i < NN) nsel[i] = (k > v || (eq && rank < R)) ? 1u : 0u;
}

// scan-based edge compaction (no atomics, deterministic); also zeroes DCNT
__global__ __launch_bounds__(1024) void k_selEdgesCompact(unsigned* WB, long sb){
  BBASE;
  const unsigned* st = B + OFF_ST;
  const unsigned* bcE = B + OFF_BC;
  const unsigned* bcG = B + OFF_BC2;
  unsigned* elist = B + OFF_ELIST;
  unsigned* dcnt = B + OFF_DCNT;
  int i = blockIdx.x * 1024 + threadIdx.x;
  if (i < NN) dcnt[i] = 0u;
  unsigned v = st[0], R = st[1], gtTot = st[4];
  unsigned k = (i < NEG) ? getkey(B, 1, i) : 0u;
  bool eq = (i < NEG) && (k == v);
  bool gt = (i < NEG) && (k > v);                   // gt implies finite key
  unsigned long long ebal = __ballot((int)eq);
  unsigned long long gbal = __ballot((int)gt);
  __shared__ unsigned wshE[16];
  __shared__ unsigned wshG[16];
  int wid = threadIdx.x >> 6, lane = threadIdx.x & 63;
  if (lane == 0){ wshE[wid] = (unsigned)__popcll(ebal); wshG[wid] = (unsigned)__popcll(gbal); }
  __syncthreads();
  unsigned eoff = 0, goff = 0;
  for (int w = 0; w < wid; w++){ eoff += wshE[w]; goff += wshG[w]; }
  unsigned long long ltm = (1ull << lane) - 1ull;
  if (gt) elist[bcG[blockIdx.x] + goff + (unsigned)__popcll(gbal & ltm)] = (unsigned)i;
  if (eq){
    unsigned rank = bcE[blockIdx.x] + eoff + (unsigned)__popcll(ebal & ltm);
    if (v > KEY_NEG_INF && rank < R) elist[gtTot + rank] = (unsigned)i;
  }
}

// ------------------------------- CSR build ----------------------------------

__global__ void k_degcnt(unsigned* WB, long sb, const int* __restrict__ edst){
  BBASE;
  const unsigned* st = B + OFF_ST;
  const unsigned* elist = B + OFF_ELIST;
  unsigned* dcnt = B + OFF_DCNT;
  unsigned i = blockIdx.x * 256 + threadIdx.x;
  if (i < st[2]) atomicAdd(dcnt + edst[elist[i]], 1u);
}

__global__ __launch_bounds__(1024) void k_blocksumsInt(unsigned* WB, long sb){
  BBASE;
  const unsigned* dcnt = B + OFF_DCNT;
  unsigned* blockcnt = B + OFF_BC;
  int i = blockIdx.x * 1024 + threadIdx.x;
  unsigned v = (i < NN) ? dcnt[i] : 0u;
  #pragma unroll
  for (int d = 1; d < 64; d <<= 1) v += (unsigned)__shfl_xor((int)v, d);
  __shared__ unsigned wsh[16];
  int wid = threadIdx.x >> 6, lane = threadIdx.x & 63;
  if (lane == 0) wsh[wid] = v;
  __syncthreads();
  if (threadIdx.x == 0){
    unsigned tot = 0;
    for (int w = 0; w < 16; w++) tot += wsh[w];
    blockcnt[blockIdx.x] = tot;
  }
}

// row starts + cursor + ACTIVE list compaction (one atomic per block)
__global__ __launch_bounds__(1024) void k_rowstartAct(unsigned* WB, long sb){
  BBASE;
  unsigned* st = B + OFF_ST;
  const unsigned* dcnt = B + OFF_DCNT;
  const unsigned* blockcnt = B + OFF_BC;
  unsigned* rowstart = B + OFF_ROWS;
  unsigned* curs = B + OFF_CURS;
  unsigned* actl = B + OFF_ACT;
  int i = blockIdx.x * 1024 + threadIdx.x;
  int wid = threadIdx.x >> 6, lane = threadIdx.x & 63;
  unsigned d = (i < NN) ? dcnt[i] : 0u;
  unsigned v = d;
  #pragma unroll
  for (int dl = 1; dl < 64; dl <<= 1){
    unsigned t2 = (unsigned)__shfl_up((int)v, dl);
    if (lane >= dl) v += t2;
  }
  bool act = (i < NN) && (d > 0u);
  unsigned long long abal = __ballot((int)act);
  __shared__ unsigned wsh[16];
  __shared__ unsigned awsh[16];
  __shared__ unsigned abase;
  if (lane == 63) wsh[wid] = v;
  if (lane == 0) awsh[wid] = (unsigned)__popcll(abal);
  __syncthreads();
  if (threadIdx.x == 0){
    unsigned tot = 0;
    for (int w = 0; w < 16; w++) tot += awsh[w];
    abase = atomicAdd(st + 3, tot);
  }
  unsigned woff = 0, aoff = 0;
  for (int w = 0; w < wid; w++){ woff += wsh[w]; aoff += awsh[w]; }
  __syncthreads();
  unsigned excl = blockcnt[blockIdx.x] + woff + (v - d);
  if (i < NN){ rowstart[i] = excl; curs[i] = excl; }
  if (act) actl[abase + aoff + (unsigned)__popcll(abal & ((1ull << lane) - 1ull))] = (unsigned)i;
}

__global__ void k_scatter(unsigned* WB, long sb, const int* __restrict__ edst){
  BBASE;
  const unsigned* st = B + OFF_ST;
  const unsigned* elist = B + OFF_ELIST;
  unsigned* curs = B + OFF_CURS;
  unsigned* csr = B + OFF_CSR;
  unsigned i = blockIdx.x * 256 + threadIdx.x;
  if (i < st[2]){
    unsigned e = elist[i];
    unsigned pos = atomicAdd(curs + edst[e], 1u);
    csr[pos] = e;
  }
}

// --------------------- fused aggregation + PNA update -----------------------

__global__ __launch_bounds__(256) void k_aggpna(unsigned* WB, long sb,
    const int* __restrict__ esrc, const int* __restrict__ etype,
    const float* __restrict__ relw, const float* __restrict__ pw,
    const float* __restrict__ pb, const float* __restrict__ gstF, int l){
  BBASE;
  const unsigned* st = B + OFF_ST;
  const unsigned* actl = B + OFF_ACT;
  const unsigned* dcnt = B + OFF_DCNT;
  const unsigned* rows = B + OFF_ROWS;
  const unsigned* csr = B + OFF_CSR;
  const float* score = (const float*)(B + OFF_SCORE);
  float* hidden = (float*)(B + OFF_HID);
  const float* relw_l = relw + (size_t)l * NR2 * 64;
  const float* pw_l = pw + (size_t)l * 768 * 64;

  int wv = (blockIdx.x * 256 + threadIdx.x) >> 6;
  int lane = threadIdx.x & 63;
  unsigned nact = st[3];
  unsigned slot0 = (unsigned)wv * 8u;
  if (slot0 >= nact) return;

  int node[8]; float degv[8];
  float smv[8], sqv[8], mxv[8], mnv[8];
  #pragma unroll
  for (int n = 0; n < 8; n++){
    unsigned s = slot0 + (unsigned)n;
    node[n] = (s < nact) ? (int)actl[s] : -1;
  }
  #pragma unroll
  for (int n = 0; n < 8; n++){
    float sm_ = 0.f, sq_ = 0.f;
    float mx_ = -__builtin_huge_valf(), mn_ = __builtin_huge_valf();
    float dv = 0.f;
    if (node[n] >= 0){
      unsigned cnt = dcnt[node[n]], rs = rows[node[n]];
      dv = (float)cnt;
      for (unsigned ii = 0; ii < cnt; ii++){
        int e = (int)csr[rs + ii];
        int s = esrc[e], t = etype[e];
        float g = 1.f / (1.f + expf(-score[s]));
        float m = g * hidden[(size_t)s*64 + lane] * relw_l[(size_t)t*64 + lane];
        sm_ += m; sq_ = fmaf(m, m, sq_);
        mx_ = fmaxf(mx_, m); mn_ = fminf(mn_, m);
      }
    }
    smv[n] = sm_; sqv[n] = sq_; mxv[n] = mx_; mnv[n] = mn_; degv[n] = dv;
  }
  float dmean = gstF[5];
  float bias = pb[(size_t)l*64 + lane];
  float acc[8];
  #pragma unroll
  for (int n = 0; n < 8; n++) acc[n] = bias;
  for (int c = 0; c < 12; c++){
    int a = c / 3, s = c - a*3;
    float wreg[64];
    #pragma unroll
    for (int k = 0; k < 64; k++) wreg[k] = pw_l[(size_t)(c*64 + k)*64 + lane];
    float fv[8];
    #pragma unroll
    for (int n = 0; n < 8; n++){
      float v = 0.f;
      if (node[n] >= 0){
        float degc = fmaxf(degv[n], 1.f);
        float logd = logf(degv[n] + 1.f);
        float scaler = (s == 0) ? 1.f : ((s == 1) ? (logd / dmean) : (dmean / fmaxf(logd, 1e-6f)));
        if (a == 0)      v = smv[n] / degc;
        else if (a == 1) v = mxv[n];
        else if (a == 2) v = mnv[n];
        else { float me = smv[n] / degc; float qv = sqv[n] / degc;
               v = sqrtf(fmaxf(qv - me*me, 0.f) + 1e-6f); }
        v *= scaler;
      }
      fv[n] = v;
    }
    #pragma unroll
    for (int k = 0; k < 64; k++){
      float w = wreg[k];
      #pragma unroll
      for (int n = 0; n < 8; n++) acc[n] = fmaf(RL(fv[n], k), w, acc[n]);
    }
  }
  #pragma unroll
  for (int n = 0; n < 8; n++)
    if (node[n] >= 0) hidden[(size_t)node[n]*64 + lane] += acc[n];
}

// ------------------------- rescore active nodes -----------------------------

__global__ __launch_bounds__(256) void k_scoreK(unsigned* WB, long sb,
    const float* __restrict__ lw, const float* __restrict__ w1,
    const float* __restrict__ b1, const float* __restrict__ w2,
    const float* __restrict__ b2){
  BBASE;
  unsigned* st = B + OFF_ST;
  if (blockIdx.x == 0 && threadIdx.x == 0){ st[0] = 0u; st[1] = KSEL; }  // next node topk
  const unsigned* actl = B + OFF_ACT;
  const float* hidden = (const float*)(B + OFF_HID);
  const float* relb = (const float*)(B + OFF_RELB);
  float* score = (float*)(B + OFF_SCORE);
  unsigned nact = st[3];
  int wv = (blockIdx.x * 256 + threadIdx.x) >> 6;
  int lane = threadIdx.x & 63;
  unsigned slot0 = (unsigned)wv * 8u;
  if (slot0 >= nact) return;
  int node[8];
  #pragma unroll
  for (int n = 0; n < 8; n++){
    unsigned s = slot0 + (unsigned)n;
    node[n] = (s < nact) ? (int)actl[s] : -1;
  }
  float wreg[64];
  #pragma unroll
  for (int k = 0; k < 64; k++) wreg[k] = lw[k*64 + lane];
  float relbv = relb[lane];
  float hidv[8];
  #pragma unroll
  for (int n = 0; n < 8; n++)
    hidv[n] = (node[n] >= 0) ? hidden[(size_t)node[n]*64 + lane] : 0.f;
  float hv[8];
  #pragma unroll
  for (int n = 0; n < 8; n++) hv[n] = relbv;
  #pragma unroll
  for (int k = 0; k < 64; k++){
    float w = wreg[k];
    #pragma unroll
    for (int n = 0; n < 8; n++) hv[n] = fmaf(RL(hidv[n], k), w, hv[n]);
  }
  float xv[8];
  #pragma unroll
  for (int n = 0; n < 8; n++) xv[n] = hidv[n] * hv[n];
  float outv[8];
  #pragma unroll
  for (int n = 0; n < 8; n++) outv[n] = 0.f;
  for (int half = 0; half < 2; half++){
    #pragma unroll
    for (int k = 0; k < 64; k++) wreg[k] = w1[k*128 + half*64 + lane];
    float a[8];
    float b1l = b1[half*64 + lane];
    #pragma unroll
    for (int n = 0; n < 8; n++) a[n] = b1l;
    #pragma unroll
    for (int k = 0; k < 64; k++){
      float w = wreg[k];
      #pragma unroll
      for (int n = 0; n < 8; n++) a[n] = fmaf(RL(xv[n], k), w, a[n]);
    }
    float w2l = w2[half*64 + lane];
    #pragma unroll
    for (int n = 0; n < 8; n++) outv[n] = fmaf(fmaxf(a[n], 0.f), w2l, outv[n]);
  }
  float b2v = b2[0];
  #pragma unroll
  for (int n = 0; n < 8; n++){
    float r = waveSumF(outv[n]);
    if (lane == 0 && node[n] >= 0) score[node[n]] = r + b2v;
  }
}

__global__ void k_out(unsigned* WB, long sb, int b0,
                      const int* __restrict__ t_index, float* __restrict__ out){
  BBASE;
  const float* score = (const float*)(B + OFF_SCORE);
  int b = b0 + blockIdx.y;
  int t = threadIdx.x;
  if (t < NTC) out[b*NTC + t] = score[t_index[b*NTC + t]];
}

// ------------------------------- launcher -----------------------------------

extern "C" void kernel_launch(void* const* d_in, const int* in_sizes, int n_in,
                              void* d_out, int out_size, void* d_ws, size_t ws_size,
                              hipStream_t stream){
  (void)in_sizes; (void)n_in; (void)out_size;
  const int*   h_index  = (const int*)d_in[0];
  const int*   r_index  = (const int*)d_in[1];
  const int*   t_index  = (const int*)d_in[2];
  const int*   all_idx  = (const int*)d_in[3];
  const int*   esrc     = (const int*)d_in[4];
  const int*   edst     = (const int*)d_in[5];
  const int*   etype    = (const int*)d_in[6];
  const float* hs       = (const float*)d_in[7];
  const float* ste      = (const float*)d_in[8];
  const float* rel_tab  = (const float*)d_in[9];
  const float* lw       = (const float*)d_in[10];
  const float* lb       = (const float*)d_in[11];
  const float* w1       = (const float*)d_in[12];
  const float* b1       = (const float*)d_in[13];
  const float* w2       = (const float*)d_in[14];
  const float* b2       = (const float*)d_in[15];
  const float* relw     = (const float*)d_in[16];
  const float* pna_w    = (const float*)d_in[17];
  const float* pna_b    = (const float*)d_in[18];
  float* out = (float*)d_out;

  unsigned* W = (unsigned*)d_ws;
  int*      LASTM = (int*)W;                    // 50000
  unsigned* DEGF  = W + 50000;                  // 50000
  float*    GSTF  = (float*)(W + 100000);       // 64
  unsigned* WB    = W + 100064;                 // batch blocks

  size_t needB = (size_t)(100064 + 4*(size_t)SBLK) * 4u;
  int nb; long sb; int nseq;
  if (ws_size >= needB){ nb = 4; sb = SBLK; nseq = 1; }
  else                 { nb = 1; sb = 0;    nseq = 4; }

  (void)hipMemsetAsync(W + 100000, 0, 64 * 4, stream);          // GSTF
  (void)hipMemsetAsync(LASTM, 0xFF, NN * 4, stream);
  (void)hipMemsetAsync(DEGF, 0, NN * 4, stream);
  for (int q = 0; q < nb; q++)
    (void)hipMemsetAsync(WB + (size_t)q*SBLK + OFF_HIST, 0, 65536 * NRHIST * 4, stream);

  const int GB_E256  = (NEG + 255) / 256;       // 6250
  const int GB_N256  = (NN + 255) / 256;        // 196
  const int GB_N1024 = (NN + 1023) / 1024;      // 49
  const int GB_E1024 = (NEG + 1023) / 1024;     // 1563
  const int GB_H     = (NN * 64) / 256;         // 12500
  const int GB_A     = 1563;                    // 4 waves x 8 slots covers 50016
  const int GB_ES    = (int)(ESEL / 256);       // 625

  k_lastm<<<(NMI + 255) / 256, 256, 0, stream>>>(all_idx, LASTM);
  k_degfull<<<GB_E256, 256, 0, stream>>>(esrc, DEGF);
  k_dsum<<<GB_N256, 256, 0, stream>>>(DEGF, GSTF);
  k_finalize<<<1, 1, 0, stream>>>(GSTF, b1, w2, b2);

  for (int q = 0; q < nseq; q++){
    int b0 = (nb == 4) ? 0 : q;
    k_relb<<<dim3(1, nb), 64, 0, stream>>>(WB, sb, b0, r_index, hs, rel_tab, lw, lb, w1, b1, w2, b2);
    k_inithidden<<<dim3(GB_H, nb), 256, 0, stream>>>(WB, sb, b0, LASTM, ste, hs, h_index);
    k_initscore<<<dim3(GB_N256, nb), 256, 0, stream>>>(WB, sb, b0, h_index, GSTF);

    for (int l = 0; l < 3; l++){
      // ---- node top-K
      k_hist<<<dim3(GB_N256, nb), 256, 0, stream>>>(WB, sb, 1, 0, NN);
      k_pick16<<<dim3(1, nb), 1024, 0, stream>>>(WB, sb, 1);
      k_hist<<<dim3(GB_N256, nb), 256, 0, stream>>>(WB, sb, 0, 0, NN);
      k_pick16<<<dim3(1, nb), 1024, 0, stream>>>(WB, sb, 0);
      k_countEq<<<dim3(GB_N1024, nb), 1024, 0, stream>>>(WB, sb, 0, NN);
      k_scanBlocks<<<dim3(1, nb), 1024, 0, stream>>>(WB, sb, GB_N1024);
      k_selNodes<<<dim3(GB_N1024, nb), 1024, 0, stream>>>(WB, sb);
      // ---- edge top-ESEL + compact (scan-based)
      k_ekey<<<dim3(GB_E256, nb), 256, 0, stream>>>(WB, sb, esrc, edst);
      k_hist<<<dim3(GB_E256, nb), 256, 0, stream>>>(WB, sb, 1, 1, NEG);
      k_pick16<<<dim3(1, nb), 1024, 0, stream>>>(WB, sb, 1);
      k_hist<<<dim3(GB_E256, nb), 256, 0, stream>>>(WB, sb, 0, 1, NEG);
      k_pick16<<<dim3(1, nb), 1024, 0, stream>>>(WB, sb, 0);
      k_countEq<<<dim3(GB_E1024, nb), 1024, 0, stream>>>(WB, sb, 1, NEG);
      k_scanBlocks2<<<dim3(1, nb), 1024, 0, stream>>>(WB, sb, GB_E1024);
      k_selEdgesCompact<<<dim3(GB_E1024, nb), 1024, 0, stream>>>(WB, sb);
      // ---- CSR by destination + active compaction
      k_degcnt<<<dim3(GB_ES, nb), 256, 0, stream>>>(WB, sb, edst);
      k_blocksumsInt<<<dim3(GB_N1024, nb), 1024, 0, stream>>>(WB, sb);
      k_scanBlocks<<<dim3(1, nb), 1024, 0, stream>>>(WB, sb, GB_N1024);
      k_rowstartAct<<<dim3(GB_N1024, nb), 1024, 0, stream>>>(WB, sb);
      k_scatter<<<dim3(GB_ES, nb), 256, 0, stream>>>(WB, sb, edst);
      // ---- fused aggregate + PNA update, then rescore
      k_aggpna<<<dim3(GB_A, nb), 256, 0, stream>>>(WB, sb, esrc, etype, relw, pna_w, pna_b, GSTF, l);
      k_scoreK<<<dim3(GB_A, nb), 256, 0, stream>>>(WB, sb, lw, w1, b1, w2, b2);
    }
    k_out<<<dim3(1, nb), 32, 0, stream>>>(WB, sb, b0, t_index, out);
  }
}

// Round 8
// 3861.040 us; speedup vs baseline: 4.2709x; 1.2983x over previous
//
#include <hip/hip_runtime.h>
#include <cstdint>
#include <cstddef>

// ---------------------------------------------------------------------------
// ConditionedPNA on MI355X, round 8.
// = round-7 PASSING kernel (5.01 ms, absmax 0.0234) with bit-identical-only
// optimizations:
//  - gate[i]=sigmoid(score[i]) precomputed once per node (in k_degcnt, stored
//    in the dead EKEY region) instead of per-edge-per-lane expf in k_aggpna.
//  - per-node aggregate values (mean/std) and degree scalers (logd/amp/att)
//    hoisted out of the 12-chunk PNA loop (identical expressions -> same bits).
//  - histogram double-buffered (HISTA for pass1, HISTB for pass0), 4 planes
//    each (same 2 MB footprint); k_pick16 no longer zeroes the histogram --
//    zeroing is folded into the next grid-wide k_countEq.
//  - k_inithidden vectorized to float4.
// NO change to any fp accumulation order that feeds scores.
// NOTE: all atomics use pointer-arithmetic form (arr + i) -- the source
// pipeline HTML-decodes "&"+identifier sequences.
// ---------------------------------------------------------------------------

#define NN   50000
#define NEG  1600000
#define NR2  1000
#define NTC  32
#define NMI  10000
#define KSEL 5000u
#define ESEL 160000u
#define KEY_NEG_INF 0x007FFFFFu
#define NRHIST 4

// per-batch workspace block offsets (u32 units)
#define OFF_ST    0         // 64   (st[0]=v st[1]=R st[2]=takeTot st[3]=nact st[4]=gtTot, stF[7]=head score)
#define OFF_RELB  64        // 64
#define OFF_BC    128       // 2048
#define OFF_BC2   2176      // 2048
#define OFF_HISTA 4224      // 65536*4 = 262144 (pass1)
#define OFF_HISTB 266368    // 65536*4 = 262144 (pass0)  [A+B contiguous 524288]
#define OFF_SCORE 528512    // 50000
#define OFF_NSEL  578512    // 50000
#define OFF_DCNT  628512    // 50000
#define OFF_ROWS  678512    // 50000
#define OFF_CURS  728512    // 50000
#define OFF_ACT   778512    // 50000
#define OFF_HID   828512    // 3200000
#define OFF_EKEY  4028512   // 1600000 (reused as f32 gate[] after edge select)
#define OFF_ELIST 5628512   // 160000
#define OFF_CSR   5788512   // 160000
#define SBLK      5948512

#define RL(x,k) __int_as_float(__builtin_amdgcn_readlane(__float_as_int(x),(k)))
#define BBASE unsigned* B = WB + (size_t)blockIdx.y * (size_t)sb

__device__ inline unsigned fkey(float f){
  unsigned u = __float_as_uint(f);
  if ((u << 1) == 0u) u = 0u;                    // canonicalize -0 -> +0
  return (u & 0x80000000u) ? ~u : (u | 0x80000000u);
}

__device__ inline float waveSumF(float v){
  #pragma unroll
  for (int d = 1; d < 64; d <<= 1) v += __shfl_xor(v, d);
  return v;
}

__device__ inline unsigned getkey(const unsigned* B, int mode, int i){
  if (mode) return (B + OFF_EKEY)[i];
  return fkey(((const float*)(B + OFF_SCORE))[i]);
}

__device__ inline void ldsHashAdd(unsigned* hkey, unsigned* hval, unsigned bin, unsigned cnt){
  unsigned h = (bin * 2654435761u) >> 23;        // 9 bits -> 0..511
  while (true){
    unsigned prev = atomicCAS(hkey + h, 0xFFFFFFFFu, bin);
    if (prev == 0xFFFFFFFFu || prev == bin){ atomicAdd(hval + h, cnt); return; }
    h = (h + 1u) & 511u;
  }
}

// ------------------------------- setup kernels ------------------------------

__global__ void k_lastm(const int* __restrict__ all_index, int* __restrict__ lastm){
  int i = blockIdx.x * 256 + threadIdx.x;
  if (i < NMI) atomicMax(lastm + all_index[i], i);
}

__global__ void k_degfull(const int* __restrict__ esrc, unsigned* __restrict__ degf){
  int i = blockIdx.x * 256 + threadIdx.x;
  if (i < NEG) atomicAdd(degf + esrc[i], 1u);
}

// dmean accumulation: per-wave f32 atomicAdd, hardware order (validated R2/R3/R7)
__global__ void k_dsum(const unsigned* __restrict__ degf, float* __restrict__ gstF){
  int i = blockIdx.x * 256 + threadIdx.x;
  float v = (i < NN) ? logf((float)degf[i] + 1.f) : 0.f;
  v = waveSumF(v);
  if ((threadIdx.x & 63) == 0) atomicAdd(gstF + 4, v);
}

__global__ void k_finalize(float* __restrict__ gstF, const float* __restrict__ b1,
                           const float* __restrict__ w2, const float* __restrict__ b2){
  gstF[5] = gstF[4] / (float)NN;                // dmean
  float s = 0.f;
  for (int m = 0; m < 128; m++) s += fmaxf(b1[m], 0.f) * w2[m];
  gstF[6] = s + b2[0];                          // base score for zero hidden
}

// ----------------------------- per-batch init -------------------------------

__global__ void k_relb(unsigned* WB, long sb, int b0,
                       const int* __restrict__ r_index, const float* __restrict__ hs,
                       const float* __restrict__ rel_table, const float* __restrict__ lw,
                       const float* __restrict__ lb, const float* __restrict__ w1,
                       const float* __restrict__ b1, const float* __restrict__ w2,
                       const float* __restrict__ b2){
  BBASE;
  float* relb = (float*)(B + OFF_RELB);
  float* stF  = (float*)(B + OFF_ST);
  int b = b0 + blockIdx.y;
  int j = threadIdx.x;                          // 64 threads, 1 wave
  int r = r_index[b];
  float acc = lb[j];
  for (int k = 0; k < 64; k++) acc = fmaf(rel_table[(size_t)r*64 + k], lw[(64 + k)*64 + j], acc);
  relb[j] = acc;
  float heur = acc;
  for (int k = 0; k < 64; k++) heur = fmaf(hs[b*64 + k], lw[k*64 + j], heur);
  float x = hs[b*64 + j] * heur;
  float o = 0.f;
  for (int half = 0; half < 2; half++){
    float a = b1[half*64 + j];
    for (int k = 0; k < 64; k++) a = fmaf(__shfl(x, k), w1[k*128 + half*64 + j], a);
    o = fmaf(fmaxf(a, 0.f), w2[half*64 + j], o);
  }
  o = waveSumF(o);
  if (j == 0) stF[7] = o + b2[0];
}

__global__ void k_inithidden(unsigned* WB, long sb, int b0,
                             const int* __restrict__ lastm, const float* __restrict__ ste,
                             const float* __restrict__ hs, const int* __restrict__ h_index){
  BBASE;
  float4* hidden = (float4*)(B + OFF_HID);
  const float4* ste4 = (const float4*)ste;
  const float4* hs4  = (const float4*)hs;
  int b = b0 + blockIdx.y;
  int idx = blockIdx.x * 256 + threadIdx.x;     // grid covers NN*16 exactly
  int n = idx >> 4, j = idx & 15;
  int h = h_index[b];
  float4 v = make_float4(0.f, 0.f, 0.f, 0.f);
  int lm = lastm[n];
  if (lm >= 0) v = ste4[(size_t)lm*16 + j];
  if (n == h)  v = hs4[b*16 + j];
  hidden[idx] = v;
}

__global__ void k_initscore(unsigned* WB, long sb, int b0,
                            const int* __restrict__ h_index, const float* __restrict__ gstF){
  BBASE;
  float* score = (float*)(B + OFF_SCORE);
  unsigned* st = B + OFF_ST;
  float* stF = (float*)st;
  int b = b0 + blockIdx.y;
  int i = blockIdx.x * 256 + threadIdx.x;
  if (i < NN) score[i] = (i == h_index[b]) ? stF[7] : gstF[6];
  if (i == 0){ st[0] = 0u; st[1] = KSEL; }
}

// ------------------------------ top-k machinery -----------------------------

__global__ void k_ekey(unsigned* WB, long sb,
                       const int* __restrict__ esrc, const int* __restrict__ edst){
  BBASE;
  unsigned* st = B + OFF_ST;
  const unsigned* nsel = B + OFF_NSEL;
  const float* score = (const float*)(B + OFF_SCORE);
  unsigned* ekey = B + OFF_EKEY;
  int i = blockIdx.x * 256 + threadIdx.x;
  if (i < NEG) ekey[i] = nsel[esrc[i]] ? fkey(score[edst[i]]) : KEY_NEG_INF;
  if (i == 0){ st[0] = 0u; st[1] = ESEL; st[2] = 0u; st[3] = 0u; st[4] = 0u; }
}

// histogram: skip KEY_NEG_INF; 2 leader rounds -> LDS hash -> replicated flush
// pass1 writes HISTA, pass0 writes HISTB (zeroed by the previous k_countEq).
__global__ __launch_bounds__(256) void k_hist(unsigned* WB, long sb, int pass, int mode, int n){
  BBASE;
  const unsigned* st = B + OFF_ST;
  unsigned* hist = B + ((pass == 1) ? OFF_HISTA : OFF_HISTB);
  __shared__ unsigned hkey[512];
  __shared__ unsigned hval[512];
  for (int t = threadIdx.x; t < 512; t += 256){ hkey[t] = 0xFFFFFFFFu; hval[t] = 0u; }
  __syncthreads();
  int i = blockIdx.x * 256 + threadIdx.x;
  unsigned bin = 0xFFFFFFFFu;
  if (i < n){
    unsigned k = getkey(B, mode, i);
    if (k != KEY_NEG_INF){
      if (pass == 1) bin = k >> 16;
      else if ((k >> 16) == (st[0] >> 16)) bin = k & 0xFFFFu;
    }
  }
  bool active = (bin != 0xFFFFFFFFu);
  int lane = threadIdx.x & 63;
  #pragma unroll
  for (int r = 0; r < 2; r++){
    unsigned long long mask = __ballot((int)active);
    if (mask != 0ull){
      int leader = __ffsll(mask) - 1;
      unsigned lbin = (unsigned)__shfl((int)bin, leader);
      bool same = active && (bin == lbin);
      unsigned long long smask = __ballot((int)same);
      if (lane == leader) ldsHashAdd(hkey, hval, lbin, (unsigned)__popcll(smask));
      if (same) active = false;
    }
  }
  if (active) ldsHashAdd(hkey, hval, bin, 1u);
  __syncthreads();
  unsigned rep = (unsigned)blockIdx.x & (NRHIST - 1u);
  for (int t = threadIdx.x; t < 512; t += 256){
    unsigned vv = hval[t];
    if (vv) atomicAdd(hist + (size_t)rep * 65536u + hkey[t], vv);
  }
}

// single block per batch: find digit containing the R-th largest; update st.
// Does NOT zero the histogram (next k_countEq does, grid-wide).
__global__ __launch_bounds__(1024) void k_pick16(unsigned* WB, long sb, int pass){
  BBASE;
  unsigned* st = B + OFF_ST;
  const unsigned* hist = B + ((pass == 1) ? OFF_HISTA : OFF_HISTB);
  __shared__ unsigned csum[1024];
  __shared__ unsigned sc[1024];
  int t = threadIdx.x;
  unsigned R = st[1];
  unsigned s = 0;
  for (int r = 0; r < NRHIST; r++){
    const unsigned* hp = hist + (size_t)r * 65536u + (unsigned)t * 64u;
    for (int b = 0; b < 64; b++) s += hp[b];
  }
  csum[t] = s; sc[t] = s; __syncthreads();
  for (int d = 1; d < 1024; d <<= 1){
    unsigned v = (t >= d) ? sc[t - d] : 0u;
    __syncthreads();
    sc[t] += v;
    __syncthreads();
  }
  unsigned total = sc[1023];
  unsigned above = total - sc[t];               // keys in higher chunks
  unsigned cs = csum[t];
  if (above < R && above + cs >= R){
    unsigned cum = above;
    for (int b = 63; b >= 0; b--){
      unsigned c = 0;
      for (int r = 0; r < NRHIST; r++) c += hist[(size_t)r * 65536u + (unsigned)(t*64 + b)];
      if (cum + c >= R){
        unsigned bstar = (unsigned)(t*64 + b);
        if (pass == 1) st[0] = bstar << 16; else st[0] = st[0] | bstar;
        st[1] = R - cum;
        break;
      }
      cum += c;
    }
  }
  if (t == 0 && total < R){                     // threshold lands in -inf bin
    if (pass == 1) st[0] = KEY_NEG_INF & 0xFFFF0000u;
    else           st[0] = st[0] | 0xFFFFu;
    st[1] = R - total;
  }
}

// per-block counts of (eq, gt) vs threshold; also zeroes both hist buffers
__global__ __launch_bounds__(1024) void k_countEq(unsigned* WB, long sb, int mode, int n){
  BBASE;
  // grid-parallel hist zeroing for the next selection phase
  unsigned* hz = B + OFF_HISTA;                  // A+B contiguous: 524288 u32
  for (unsigned j = blockIdx.x * 1024u + threadIdx.x; j < 524288u; j += gridDim.x * 1024u)
    hz[j] = 0u;
  const unsigned* st = B + OFF_ST;
  unsigned* bcE = B + OFF_BC;
  unsigned* bcG = B + OFF_BC2;
  int i = blockIdx.x * 1024 + threadIdx.x;
  unsigned v = st[0];
  unsigned k = (i < n) ? getkey(B, mode, i) : 0u;
  bool eq = (i < n) && (k == v);
  bool gt = (i < n) && (k > v);
  unsigned long long ebal = __ballot((int)eq);
  unsigned long long gbal = __ballot((int)gt);
  __shared__ unsigned wshE[16];
  __shared__ unsigned wshG[16];
  int wid = threadIdx.x >> 6, lane = threadIdx.x & 63;
  if (lane == 0){ wshE[wid] = (unsigned)__popcll(ebal); wshG[wid] = (unsigned)__popcll(gbal); }
  __syncthreads();
  if (threadIdx.x == 0){
    unsigned te = 0, tg = 0;
    for (int w = 0; w < 16; w++){ te += wshE[w]; tg += wshG[w]; }
    bcE[blockIdx.x] = te; bcG[blockIdx.x] = tg;
  }
}

__global__ __launch_bounds__(1024) void k_scanBlocks(unsigned* WB, long sb, int nbk){
  BBASE;
  unsigned* blockcnt = B + OFF_BC;
  __shared__ unsigned sc[2048];
  int t = threadIdx.x;
  unsigned a  = (t < nbk) ? blockcnt[t] : 0u;
  unsigned b2 = (1024 + t < nbk) ? blockcnt[1024 + t] : 0u;
  sc[t] = a; sc[1024 + t] = b2; __syncthreads();
  for (int d = 1; d < 2048; d <<= 1){
    unsigned v1 = (t >= d) ? sc[t - d] : 0u;
    unsigned v2 = (1024 + t >= d) ? sc[1024 + t - d] : 0u;
    __syncthreads();
    sc[t] += v1; sc[1024 + t] += v2;
    __syncthreads();
  }
  if (t < nbk) blockcnt[t] = sc[t] - a;             // exclusive
  if (1024 + t < nbk) blockcnt[1024 + t] = sc[1024 + t] - b2;
}

// dual scan (eq + gt) for edge compaction; also computes st[2], st[4]
__global__ __launch_bounds__(1024) void k_scanBlocks2(unsigned* WB, long sb, int nbk){
  BBASE;
  unsigned* st = B + OFF_ST;
  unsigned* bcE = B + OFF_BC;
  unsigned* bcG = B + OFF_BC2;
  __shared__ unsigned se[2048];
  __shared__ unsigned sg[2048];
  int t = threadIdx.x;
  unsigned e0 = (t < nbk) ? bcE[t] : 0u;
  unsigned e1 = (1024 + t < nbk) ? bcE[1024 + t] : 0u;
  unsigned g0 = (t < nbk) ? bcG[t] : 0u;
  unsigned g1 = (1024 + t < nbk) ? bcG[1024 + t] : 0u;
  se[t] = e0; se[1024 + t] = e1; sg[t] = g0; sg[1024 + t] = g1;
  __syncthreads();
  for (int d = 1; d < 2048; d <<= 1){
    unsigned a1 = (t >= d) ? se[t - d] : 0u;
    unsigned a2 = (1024 + t >= d) ? se[1024 + t - d] : 0u;
    unsigned c1 = (t >= d) ? sg[t - d] : 0u;
    unsigned c2 = (1024 + t >= d) ? sg[1024 + t - d] : 0u;
    __syncthreads();
    se[t] += a1; se[1024 + t] += a2; sg[t] += c1; sg[1024 + t] += c2;
    __syncthreads();
  }
  if (t < nbk) bcE[t] = se[t] - e0;
  if (1024 + t < nbk) bcE[1024 + t] = se[1024 + t] - e1;
  if (t < nbk) bcG[t] = sg[t] - g0;
  if (1024 + t < nbk) bcG[1024 + t] = sg[1024 + t] - g1;
  if (t == 0){
    unsigned gtTot = sg[2047];
    st[4] = gtTot;
    st[2] = gtTot + ((st[0] > KEY_NEG_INF) ? st[1] : 0u);  // R' <= eqTot always
  }
}

__global__ __launch_bounds__(1024) void k_selNodes(unsigned* WB, long sb){
  BBASE;
  const unsigned* st = B + OFF_ST;
  const unsigned* blockcnt = B + OFF_BC;
  unsigned* nsel = B + OFF_NSEL;
  int i = blockIdx.x * 1024 + threadIdx.x;
  unsigned v = st[0], R = st[1];
  unsigned k = (i < NN) ? getkey(B, 0, i) : 0u;
  bool eq = (i < NN) && (k == v);
  unsigned long long bal = __ballot((int)eq);
  __shared__ unsigned wsh[16];
  int wid = threadIdx.x >> 6, lane = threadIdx.x & 63;
  if (lane == 0) wsh[wid] = (unsigned)__popcll(bal);
  __syncthreads();
  unsigned woff = 0;
  for (int w = 0; w < wid; w++) woff += wsh[w];
  unsigned lpre = (unsigned)__popcll(bal & ((1ull << lane) - 1ull));
  unsigned rank = blockcnt[blockIdx.x] + woff + lpre;
  if (i < NN) nsel[i] = (k > v || (eq && rank < R)) ? 1u : 0u;
}

// scan-based edge compaction (no atomics, deterministic); also zeroes DCNT
__global__ __launch_bounds__(1024) void k_selEdgesCompact(unsigned* WB, long sb){
  BBASE;
  const unsigned* st = B + OFF_ST;
  const unsigned* bcE = B + OFF_BC;
  const unsigned* bcG = B + OFF_BC2;
  unsigned* elist = B + OFF_ELIST;
  unsigned* dcnt = B + OFF_DCNT;
  int i = blockIdx.x * 1024 + threadIdx.x;
  if (i < NN) dcnt[i] = 0u;
  unsigned v = st[0], R = st[1], gtTot = st[4];
  unsigned k = (i < NEG) ? getkey(B, 1, i) : 0u;
  bool eq = (i < NEG) && (k == v);
  bool gt = (i < NEG) && (k > v);                   // gt implies finite key
  unsigned long long ebal = __ballot((int)eq);
  unsigned long long gbal = __ballot((int)gt);
  __shared__ unsigned wshE[16];
  __shared__ unsigned wshG[16];
  int wid = threadIdx.x >> 6, lane = threadIdx.x & 63;
  if (lane == 0){ wshE[wid] = (unsigned)__popcll(ebal); wshG[wid] = (unsigned)__popcll(gbal); }
  __syncthreads();
  unsigned eoff = 0, goff = 0;
  for (int w = 0; w < wid; w++){ eoff += wshE[w]; goff += wshG[w]; }
  unsigned long long ltm = (1ull << lane) - 1ull;
  if (gt) elist[bcG[blockIdx.x] + goff + (unsigned)__popcll(gbal & ltm)] = (unsigned)i;
  if (eq){
    unsigned rank = bcE[blockIdx.x] + eoff + (unsigned)__popcll(ebal & ltm);
    if (v > KEY_NEG_INF && rank < R) elist[gtTot + rank] = (unsigned)i;
  }
}

// ------------------------------- CSR build ----------------------------------

// dcnt accumulation + gate precompute (EKEY region is dead after edge select)
__global__ void k_degcnt(unsigned* WB, long sb, const int* __restrict__ edst){
  BBASE;
  const unsigned* st = B + OFF_ST;
  const unsigned* elist = B + OFF_ELIST;
  unsigned* dcnt = B + OFF_DCNT;
  const float* score = (const float*)(B + OFF_SCORE);
  float* gate = (float*)(B + OFF_EKEY);
  unsigned i = blockIdx.x * 256 + threadIdx.x;
  if (i < NN) gate[i] = 1.f / (1.f + expf(-score[i]));   // same formula as before
  if (i < st[2]) atomicAdd(dcnt + edst[elist[i]], 1u);
}

__global__ __launch_bounds__(1024) void k_blocksumsInt(unsigned* WB, long sb){
  BBASE;
  const unsigned* dcnt = B + OFF_DCNT;
  unsigned* blockcnt = B + OFF_BC;
  int i = blockIdx.x * 1024 + threadIdx.x;
  unsigned v = (i < NN) ? dcnt[i] : 0u;
  #pragma unroll
  for (int d = 1; d < 64; d <<= 1) v += (unsigned)__shfl_xor((int)v, d);
  __shared__ unsigned wsh[16];
  int wid = threadIdx.x >> 6, lane = threadIdx.x & 63;
  if (lane == 0) wsh[wid] = v;
  __syncthreads();
  if (threadIdx.x == 0){
    unsigned tot = 0;
    for (int w = 0; w < 16; w++) tot += wsh[w];
    blockcnt[blockIdx.x] = tot;
  }
}

// row starts + cursor + ACTIVE list compaction (one atomic per block)
__global__ __launch_bounds__(1024) void k_rowstartAct(unsigned* WB, long sb){
  BBASE;
  unsigned* st = B + OFF_ST;
  const unsigned* dcnt = B + OFF_DCNT;
  const unsigned* blockcnt = B + OFF_BC;
  unsigned* rowstart = B + OFF_ROWS;
  unsigned* curs = B + OFF_CURS;
  unsigned* actl = B + OFF_ACT;
  int i = blockIdx.x * 1024 + threadIdx.x;
  int wid = threadIdx.x >> 6, lane = threadIdx.x & 63;
  unsigned d = (i < NN) ? dcnt[i] : 0u;
  unsigned v = d;
  #pragma unroll
  for (int dl = 1; dl < 64; dl <<= 1){
    unsigned t2 = (unsigned)__shfl_up((int)v, dl);
    if (lane >= dl) v += t2;
  }
  bool act = (i < NN) && (d > 0u);
  unsigned long long abal = __ballot((int)act);
  __shared__ unsigned wsh[16];
  __shared__ unsigned awsh[16];
  __shared__ unsigned abase;
  if (lane == 63) wsh[wid] = v;
  if (lane == 0) awsh[wid] = (unsigned)__popcll(abal);
  __syncthreads();
  if (threadIdx.x == 0){
    unsigned tot = 0;
    for (int w = 0; w < 16; w++) tot += awsh[w];
    abase = atomicAdd(st + 3, tot);
  }
  unsigned woff = 0, aoff = 0;
  for (int w = 0; w < wid; w++){ woff += wsh[w]; aoff += awsh[w]; }
  __syncthreads();
  unsigned excl = blockcnt[blockIdx.x] + woff + (v - d);
  if (i < NN){ rowstart[i] = excl; curs[i] = excl; }
  if (act) actl[abase + aoff + (unsigned)__popcll(abal & ((1ull << lane) - 1ull))] = (unsigned)i;
}

__global__ void k_scatter(unsigned* WB, long sb, const int* __restrict__ edst){
  BBASE;
  const unsigned* st = B + OFF_ST;
  const unsigned* elist = B + OFF_ELIST;
  unsigned* curs = B + OFF_CURS;
  unsigned* csr = B + OFF_CSR;
  unsigned i = blockIdx.x * 256 + threadIdx.x;
  if (i < st[2]){
    unsigned e = elist[i];
    unsigned pos = atomicAdd(curs + edst[e], 1u);
    csr[pos] = e;
  }
}

// --------------------- fused aggregation + PNA update -----------------------

__global__ __launch_bounds__(256) void k_aggpna(unsigned* WB, long sb,
    const int* __restrict__ esrc, const int* __restrict__ etype,
    const float* __restrict__ relw, const float* __restrict__ pw,
    const float* __restrict__ pb, const float* __restrict__ gstF, int l){
  BBASE;
  const unsigned* st = B + OFF_ST;
  const unsigned* actl = B + OFF_ACT;
  const unsigned* dcnt = B + OFF_DCNT;
  const unsigned* rows = B + OFF_ROWS;
  const unsigned* csr = B + OFF_CSR;
  const float* gate = (const float*)(B + OFF_EKEY);
  float* hidden = (float*)(B + OFF_HID);
  const float* relw_l = relw + (size_t)l * NR2 * 64;
  const float* pw_l = pw + (size_t)l * 768 * 64;

  int wv = (blockIdx.x * 256 + threadIdx.x) >> 6;
  int lane = threadIdx.x & 63;
  unsigned nact = st[3];
  unsigned slot0 = (unsigned)wv * 8u;
  if (slot0 >= nact) return;

  int node[8];
  float aggm[8], aggx[8], aggn[8], aggs[8];   // mean, max, min, std
  float ampv[8], attv[8];
  #pragma unroll
  for (int n = 0; n < 8; n++){
    unsigned s = slot0 + (unsigned)n;
    node[n] = (s < nact) ? (int)actl[s] : -1;
  }
  float dmean = gstF[5];
  #pragma unroll
  for (int n = 0; n < 8; n++){
    float sm_ = 0.f, sq_ = 0.f;
    float mx_ = -__builtin_huge_valf(), mn_ = __builtin_huge_valf();
    float dv = 0.f;
    if (node[n] >= 0){
      unsigned cnt = dcnt[node[n]], rs = rows[node[n]];
      dv = (float)cnt;
      for (unsigned ii = 0; ii < cnt; ii++){
        int e = (int)csr[rs + ii];
        int s = esrc[e], t = etype[e];
        float g = gate[s];
        float m = g * hidden[(size_t)s*64 + lane] * relw_l[(size_t)t*64 + lane];
        sm_ += m; sq_ = fmaf(m, m, sq_);
        mx_ = fmaxf(mx_, m); mn_ = fminf(mn_, m);
      }
    }
    // hoisted per-node aggregates & scalers (identical expressions to R7)
    if (node[n] >= 0){
      float degc = fmaxf(dv, 1.f);
      float me = sm_ / degc;
      float qv = sq_ / degc;
      aggm[n] = me;
      aggs[n] = sqrtf(fmaxf(qv - me*me, 0.f) + 1e-6f);
      aggx[n] = mx_; aggn[n] = mn_;
      float logd = logf(dv + 1.f);
      ampv[n] = logd / dmean;
      attv[n] = dmean / fmaxf(logd, 1e-6f);
    } else { aggm[n] = 0.f; aggs[n] = 0.f; aggx[n] = 0.f; aggn[n] = 0.f; ampv[n] = 0.f; attv[n] = 0.f; }
  }
  float bias = pb[(size_t)l*64 + lane];
  float acc[8];
  #pragma unroll
  for (int n = 0; n < 8; n++) acc[n] = bias;
  for (int c = 0; c < 12; c++){
    int a = c / 3, s = c - a*3;
    float wreg[64];
    #pragma unroll
    for (int k = 0; k < 64; k++) wreg[k] = pw_l[(size_t)(c*64 + k)*64 + lane];
    float fv[8];
    #pragma unroll
    for (int n = 0; n < 8; n++){
      float v = 0.f;
      if (node[n] >= 0){
        if (a == 0)      v = aggm[n];
        else if (a == 1) v = aggx[n];
        else if (a == 2) v = aggn[n];
        else             v = aggs[n];
        float scaler = (s == 0) ? 1.f : ((s == 1) ? ampv[n] : attv[n]);
        v *= scaler;
      }
      fv[n] = v;
    }
    #pragma unroll
    for (int k = 0; k < 64; k++){
      float w = wreg[k];
      #pragma unroll
      for (int n = 0; n < 8; n++) acc[n] = fmaf(RL(fv[n], k), w, acc[n]);
    }
  }
  #pragma unroll
  for (int n = 0; n < 8; n++)
    if (node[n] >= 0) hidden[(size_t)node[n]*64 + lane] += acc[n];
}

// ------------------------- rescore active nodes -----------------------------

__global__ __launch_bounds__(256) void k_scoreK(unsigned* WB, long sb,
    const float* __restrict__ lw, const float* __restrict__ w1,
    const float* __restrict__ b1, const float* __restrict__ w2,
    const float* __restrict__ b2){
  BBASE;
  unsigned* st = B + OFF_ST;
  if (blockIdx.x == 0 && threadIdx.x == 0){ st[0] = 0u; st[1] = KSEL; }  // next node topk
  const unsigned* actl = B + OFF_ACT;
  const float* hidden = (const float*)(B + OFF_HID);
  const float* relb = (const float*)(B + OFF_RELB);
  float* score = (float*)(B + OFF_SCORE);
  unsigned nact = st[3];
  int wv = (blockIdx.x * 256 + threadIdx.x) >> 6;
  int lane = threadIdx.x & 63;
  unsigned slot0 = (unsigned)wv * 8u;
  if (slot0 >= nact) return;
  int node[8];
  #pragma unroll
  for (int n = 0; n < 8; n++){
    unsigned s = slot0 + (unsigned)n;
    node[n] = (s < nact) ? (int)actl[s] : -1;
  }
  float wreg[64];
  #pragma unroll
  for (int k = 0; k < 64; k++) wreg[k] = lw[k*64 + lane];
  float relbv = relb[lane];
  float hidv[8];
  #pragma unroll
  for (int n = 0; n < 8; n++)
    hidv[n] = (node[n] >= 0) ? hidden[(size_t)node[n]*64 + lane] : 0.f;
  float hv[8];
  #pragma unroll
  for (int n = 0; n < 8; n++) hv[n] = relbv;
  #pragma unroll
  for (int k = 0; k < 64; k++){
    float w = wreg[k];
    #pragma unroll
    for (int n = 0; n < 8; n++) hv[n] = fmaf(RL(hidv[n], k), w, hv[n]);
  }
  float xv[8];
  #pragma unroll
  for (int n = 0; n < 8; n++) xv[n] = hidv[n] * hv[n];
  float outv[8];
  #pragma unroll
  for (int n = 0; n < 8; n++) outv[n] = 0.f;
  for (int half = 0; half < 2; half++){
    #pragma unroll
    for (int k = 0; k < 64; k++) wreg[k] = w1[k*128 + half*64 + lane];
    float a[8];
    float b1l = b1[half*64 + lane];
    #pragma unroll
    for (int n = 0; n < 8; n++) a[n] = b1l;
    #pragma unroll
    for (int k = 0; k < 64; k++){
      float w = wreg[k];
      #pragma unroll
      for (int n = 0; n < 8; n++) a[n] = fmaf(RL(xv[n], k), w, a[n]);
    }
    float w2l = w2[half*64 + lane];
    #pragma unroll
    for (int n = 0; n < 8; n++) outv[n] = fmaf(fmaxf(a[n], 0.f), w2l, outv[n]);
  }
  float b2v = b2[0];
  #pragma unroll
  for (int n = 0; n < 8; n++){
    float r = waveSumF(outv[n]);
    if (lane == 0 && node[n] >= 0) score[node[n]] = r + b2v;
  }
}

__global__ void k_out(unsigned* WB, long sb, int b0,
                      const int* __restrict__ t_index, float* __restrict__ out){
  BBASE;
  const float* score = (const float*)(B + OFF_SCORE);
  int b = b0 + blockIdx.y;
  int t = threadIdx.x;
  if (t < NTC) out[b*NTC + t] = score[t_index[b*NTC + t]];
}

// ------------------------------- launcher -----------------------------------

extern "C" void kernel_launch(void* const* d_in, const int* in_sizes, int n_in,
                              void* d_out, int out_size, void* d_ws, size_t ws_size,
                              hipStream_t stream){
  (void)in_sizes; (void)n_in; (void)out_size;
  const int*   h_index  = (const int*)d_in[0];
  const int*   r_index  = (const int*)d_in[1];
  const int*   t_index  = (const int*)d_in[2];
  const int*   all_idx  = (const int*)d_in[3];
  const int*   esrc     = (const int*)d_in[4];
  const int*   edst     = (const int*)d_in[5];
  const int*   etype    = (const int*)d_in[6];
  const float* hs       = (const float*)d_in[7];
  const float* ste      = (const float*)d_in[8];
  const float* rel_tab  = (const float*)d_in[9];
  const float* lw       = (const float*)d_in[10];
  const float* lb       = (const float*)d_in[11];
  const float* w1       = (const float*)d_in[12];
  const float* b1       = (const float*)d_in[13];
  const float* w2       = (const float*)d_in[14];
  const float* b2       = (const float*)d_in[15];
  const float* relw     = (const float*)d_in[16];
  const float* pna_w    = (const float*)d_in[17];
  const float* pna_b    = (const float*)d_in[18];
  float* out = (float*)d_out;

  unsigned* W = (unsigned*)d_ws;
  int*      LASTM = (int*)W;                    // 50000
  unsigned* DEGF  = W + 50000;                  // 50000
  float*    GSTF  = (float*)(W + 100000);       // 64
  unsigned* WB    = W + 100064;                 // batch blocks

  size_t needB = (size_t)(100064 + 4*(size_t)SBLK) * 4u;
  int nb; long sb; int nseq;
  if (ws_size >= needB){ nb = 4; sb = SBLK; nseq = 1; }
  else                 { nb = 1; sb = 0;    nseq = 4; }

  (void)hipMemsetAsync(W + 100000, 0, 64 * 4, stream);          // GSTF
  (void)hipMemsetAsync(LASTM, 0xFF, NN * 4, stream);
  (void)hipMemsetAsync(DEGF, 0, NN * 4, stream);
  for (int q = 0; q < nb; q++)
    (void)hipMemsetAsync(WB + (size_t)q*SBLK + OFF_HISTA, 0, 524288 * 4, stream);

  const int GB_E256  = (NEG + 255) / 256;       // 6250
  const int GB_N256  = (NN + 255) / 256;        // 196
  const int GB_N1024 = (NN + 1023) / 1024;      // 49
  const int GB_E1024 = (NEG + 1023) / 1024;     // 1563
  const int GB_H4    = (NN * 16) / 256;         // 3125 (float4 rows)
  const int GB_A     = 1563;                    // 4 waves x 8 slots covers 50016
  const int GB_ES    = (int)(ESEL / 256);       // 625

  k_lastm<<<(NMI + 255) / 256, 256, 0, stream>>>(all_idx, LASTM);
  k_degfull<<<GB_E256, 256, 0, stream>>>(esrc, DEGF);
  k_dsum<<<GB_N256, 256, 0, stream>>>(DEGF, GSTF);
  k_finalize<<<1, 1, 0, stream>>>(GSTF, b1, w2, b2);

  for (int q = 0; q < nseq; q++){
    int b0 = (nb == 4) ? 0 : q;
    k_relb<<<dim3(1, nb), 64, 0, stream>>>(WB, sb, b0, r_index, hs, rel_tab, lw, lb, w1, b1, w2, b2);
    k_inithidden<<<dim3(GB_H4, nb), 256, 0, stream>>>(WB, sb, b0, LASTM, ste, hs, h_index);
    k_initscore<<<dim3(GB_N256, nb), 256, 0, stream>>>(WB, sb, b0, h_index, GSTF);

    for (int l = 0; l < 3; l++){
      // ---- node top-K
      k_hist<<<dim3(GB_N256, nb), 256, 0, stream>>>(WB, sb, 1, 0, NN);
      k_pick16<<<dim3(1, nb), 1024, 0, stream>>>(WB, sb, 1);
      k_hist<<<dim3(GB_N256, nb), 256, 0, stream>>>(WB, sb, 0, 0, NN);
      k_pick16<<<dim3(1, nb), 1024, 0, stream>>>(WB, sb, 0);
      k_countEq<<<dim3(GB_N1024, nb), 1024, 0, stream>>>(WB, sb, 0, NN);   // + zeroes hists
      k_scanBlocks<<<dim3(1, nb), 1024, 0, stream>>>(WB, sb, GB_N1024);
      k_selNodes<<<dim3(GB_N1024, nb), 1024, 0, stream>>>(WB, sb);
      // ---- edge top-ESEL + compact (scan-based)
      k_ekey<<<dim3(GB_E256, nb), 256, 0, stream>>>(WB, sb, esrc, edst);
      k_hist<<<dim3(GB_E256, nb), 256, 0, stream>>>(WB, sb, 1, 1, NEG);
      k_pick16<<<dim3(1, nb), 1024, 0, stream>>>(WB, sb, 1);
      k_hist<<<dim3(GB_E256, nb), 256, 0, stream>>>(WB, sb, 0, 1, NEG);
      k_pick16<<<dim3(1, nb), 1024, 0, stream>>>(WB, sb, 0);
      k_countEq<<<dim3(GB_E1024, nb), 1024, 0, stream>>>(WB, sb, 1, NEG);  // + zeroes hists
      k_scanBlocks2<<<dim3(1, nb), 1024, 0, stream>>>(WB, sb, GB_E1024);
      k_selEdgesCompact<<<dim3(GB_E1024, nb), 1024, 0, stream>>>(WB, sb);
      // ---- CSR by destination + active compaction (+ gate precompute)
      k_degcnt<<<dim3(GB_ES, nb), 256, 0, stream>>>(WB, sb, edst);
      k_blocksumsInt<<<dim3(GB_N1024, nb), 1024, 0, stream>>>(WB, sb);
      k_scanBlocks<<<dim3(1, nb), 1024, 0, stream>>>(WB, sb, GB_N1024);
      k_rowstartAct<<<dim3(GB_N1024, nb), 1024, 0, stream>>>(WB, sb);
      k_scatter<<<dim3(GB_ES, nb), 256, 0, stream>>>(WB, sb, edst);
      // ---- fused aggregate + PNA update, then rescore
      k_aggpna<<<dim3(GB_A, nb), 256, 0, stream>>>(WB, sb, esrc, etype, relw, pna_w, pna_b, GSTF, l);
      k_scoreK<<<dim3(GB_A, nb), 256, 0, stream>>>(WB, sb, lw, w1, b1, w2, b2);
    }
    k_out<<<dim3(1, nb), 32, 0, stream>>>(WB, sb, b0, t_index, out);
  }
}